// Round 8
// baseline (471.793 us; speedup 1.0000x reference)
//
#include <hip/hip_runtime.h>
#include <hip/hip_bf16.h>
#include <math.h>

#define H 256
#define F 16
#define MUL 16
#define NB 8
#define LROW 296   // As row stride (elems): 148 dwords == 20 mod 32 -> 2-way (free)

typedef short bf16x8 __attribute__((ext_vector_type(8)));
typedef short bf16x4 __attribute__((ext_vector_type(4)));
typedef float f32x4 __attribute__((ext_vector_type(4)));
#define MFMA_B16(a, b, c) __builtin_amdgcn_mfma_f32_16x16x32_bf16(a, b, c, 0, 0, 0)

__device__ __forceinline__ float bf2f(__hip_bfloat16 x) { return __bfloat162float(x); }
__device__ __forceinline__ float silu(float x) { return x / (1.f + __expf(-x)); }
__device__ __forceinline__ short f2bs(float x)
{
    __hip_bfloat16 h = __float2bfloat16(x);
    short s; __builtin_memcpy(&s, &h, 2); return s;
}
__device__ __forceinline__ float bs2f(short s)
{
    __hip_bfloat16 h; __builtin_memcpy(&h, &s, 2); return __bfloat162float(h);
}

// ---------------- dtype sniffer: bf16 (flag=0) or fp32 (flag=1)?
__global__ __launch_bounds__(256) void k_sniff(const void* vec, int* flag)
{
    __shared__ int bad;
    int tid = threadIdx.x;
    if (tid == 0) bad = 0;
    __syncthreads();
    const __hip_bfloat16* hp = (const __hip_bfloat16*)vec;
    for (int i = tid; i < 1024; i += 256) {
        float f = bf2f(hp[i]);
        if (!(isfinite(f) && fabsf(f) <= 1.0f)) bad = 1;
    }
    __syncthreads();
    if (tid == 0) *flag = bad;
}

// ---------------- merged converter: 14 float inputs -> canonical fp32
struct ConvArgs {
    const void* src[14];
    float* dst[14];
    int cum[15];
};
__global__ __launch_bounds__(256) void k_conv_all(ConvArgs a, const int* __restrict__ flag)
{
    int gid = blockIdx.x * 256 + threadIdx.x;
    if (gid >= a.cum[14]) return;
    int k = 0;
    while (gid >= a.cum[k + 1]) k++;
    int i = gid - a.cum[k];
    float v = (*flag) ? ((const float*)a.src[k])[i]
                      : bf2f(((const __hip_bfloat16*)a.src[k])[i]);
    a.dst[k][i] = v;
}

// ---------------- merged weight swizzle: fp32 [K][N] -> bf16 frag-linear
struct SwzArgs {
    const float* src[9];
    __hip_bfloat16* dst[9];
    int K[9], Nc[9], cum[10];
};
__global__ __launch_bounds__(256) void k_swz_all(SwzArgs a)
{
    int gid = blockIdx.x * 256 + threadIdx.x;
    if (gid >= a.cum[9]) return;
    int j = 0;
    while (gid >= a.cum[j + 1]) j++;
    int idx = gid - a.cum[j];
    int kk = idx & 31;
    int n = (idx >> 5) % a.Nc[j];
    int kt = idx / (32 * a.Nc[j]);
    int k = kt * 32 + kk;
    float v = (k < a.K[j]) ? a.src[j][(size_t)k * a.Nc[j] + n] : 0.f;
    a.dst[j][idx] = __float2bfloat16(v);
}

// ---------------- W_out swizzle: [256][1] -> frag-linear [256x16], col 0 only
__global__ __launch_bounds__(256) void k_swz_wout(const float* __restrict__ Wout,
                                                  __hip_bfloat16* __restrict__ dst)
{
    int idx = blockIdx.x * 256 + threadIdx.x;   // 4096 total
    if (idx >= 8 * 16 * 32) return;
    int kk = idx & 31;
    int n = (idx >> 5) & 15;
    int kt = idx >> 9;
    float v = (n == 0) ? Wout[kt * 32 + kk] : 0.f;
    dst[idx] = __float2bfloat16(v);
}

// ---------------- CSR build
__global__ __launch_bounds__(256) void k_hist(const int* __restrict__ snd,
                                              int* __restrict__ cnt, int E)
{
    int e = blockIdx.x * 256 + threadIdx.x;
    if (e < E) atomicAdd(&cnt[snd[e]], 1);
}

__global__ __launch_bounds__(256) void k_scan(const int* __restrict__ cnt,
                                              int* __restrict__ off,
                                              int* __restrict__ cur, int N)
{
    __shared__ int sums[256];
    int tid = threadIdx.x;
    int chunk = (N + 255) / 256;
    int base = tid * chunk;
    int s = 0;
    for (int i = 0; i < chunk; i++) { int idx = base + i; if (idx < N) s += cnt[idx]; }
    sums[tid] = s;
    __syncthreads();
    for (int d = 1; d < 256; d <<= 1) {
        int v = (tid >= d) ? sums[tid - d] : 0;
        __syncthreads();
        sums[tid] += v;
        __syncthreads();
    }
    int run = (tid == 0) ? 0 : sums[tid - 1];
    for (int i = 0; i < chunk; i++) {
        int idx = base + i;
        if (idx < N) { off[idx] = run; cur[idx] = run; run += cnt[idx]; }
    }
    if (tid == 255) off[N] = run;
}

__global__ __launch_bounds__(256) void k_cscatter(const int* __restrict__ snd,
                                                  int* __restrict__ cur,
                                                  int* __restrict__ eidx, int E)
{
    int e = blockIdx.x * 256 + threadIdx.x;
    if (e >= E) return;
    int p = atomicAdd(&cur[snd[e]], 1);
    eidx[p] = e;
}

// =====================================================================
// Tile kernels (operand-swapped): A-operand = weight frag, B-operand = x frag
// Block = 64 edges x 8 waves (512 thr); wave w owns outcol slice 32w..32w+31.
// SINGLE LDS buffer As (38 KB) at __launch_bounds__(512,6) -> 3 blocks/CU,
// 24 waves/CU. Occupancy-vs-L2 model (r3/r4/r7 post-mortems): active
// epilogue write-lines = blocks/CU*256CU*32KB; 4 blk = 33MB > 32MB L2
// (thrash: WRITE 342MB), 2 blk = 16MB (fine), 3 blk = 25MB (fits).
// xb stream-out uses NONTEMPORAL stores: lines are only re-read by the
// NEXT dispatch (L3-served), so keep them out of L2's retention set.
// x_old in registers; vv precomputed node-grouped (r5).
// =====================================================================

// ---------------- MFMA embed tile kernel with fused geometry prologue
__global__ __launch_bounds__(512, 6) void k_embed_mfma(
    const float* __restrict__ vec, const float* __restrict__ na,
    const int* __restrict__ snd, const int* __restrict__ rcv,
    const __hip_bfloat16* __restrict__ We0s, const float* __restrict__ be0,
    const __hip_bfloat16* __restrict__ We1s, const float* __restrict__ be1,
    const __hip_bfloat16* __restrict__ Wv0s, const __hip_bfloat16* __restrict__ Wlws0,
    float* __restrict__ ubuf, float* __restrict__ Ybuf,
    __hip_bfloat16* __restrict__ xb, float* __restrict__ abuf,
    float* __restrict__ wbuf)
{
    __shared__ __align__(16) __hip_bfloat16 As[64 * LROW];  // 37888 B
    __shared__ float us[64];
    int tid = threadIdx.x;
    int w = tid >> 6, l = tid & 63;
    int lm = l & 15, lq = l >> 4;
    int eb = blockIdx.x * 64;

    // ---- fused geometry: features straight into As; u,Y to global ----
    {
        int el = tid & 63;
        int part = tid >> 6;
        int ge = eb + el;
        const float SQ2 = 1.41421356237309515f;
        const float PI = 3.14159265358979323846f;
        if (part == 0) {
            float vx = vec[3 * ge + 0], vy = vec[3 * ge + 1], vz = vec[3 * ge + 2];
            float d = sqrtf(vx * vx + vy * vy + vz * vz);
            float d3 = d * d * d;
            float d6 = d3 * d3, d7 = d6 * d, d8 = d7 * d;
            float u = 1.f - 28.f * d6 + 48.f * d7 - 21.f * d8;
            u = (d < 1.f) ? u : 0.f;
            ubuf[ge] = u;
            us[el] = u;
            float invd = 1.f / d;
#pragma unroll
            for (int k = 1; k <= 4; k++)
                As[el * LROW + (k - 1)] = __float2bfloat16(SQ2 * sinf((float)k * PI * d) * invd);
        } else if (part == 4) {
            float vx = vec[3 * ge + 0], vy = vec[3 * ge + 1], vz = vec[3 * ge + 2];
            float d = sqrtf(vx * vx + vy * vy + vz * vz);
            float invd = 1.f / d;
#pragma unroll
            for (int k = 5; k <= 8; k++)
                As[el * LROW + (k - 1)] = __float2bfloat16(SQ2 * sinf((float)k * PI * d) * invd);
        } else if (part == 5) {
#pragma unroll
            for (int j = 40; j < 64; j++) As[el * LROW + j] = __float2bfloat16(0.f);
        } else if (part == 1) {
            int s = snd[ge];
#pragma unroll
            for (int j = 0; j < 16; j++)
                As[el * LROW + 8 + j] = __float2bfloat16(na[(size_t)s * F + j]);
        } else if (part == 2) {
            int r = rcv[ge];
#pragma unroll
            for (int j = 0; j < 16; j++)
                As[el * LROW + 24 + j] = __float2bfloat16(na[(size_t)r * F + j]);
        } else if (part == 3) {
            float vx = vec[3 * ge + 0], vy = vec[3 * ge + 1], vz = vec[3 * ge + 2];
            float d = sqrtf(vx * vx + vy * vy + vz * vz);
            float invd = 1.f / d;
            float x = vx * invd, y = vy * invd, z = vz * invd;
            const float s3 = 1.7320508075688772f;
            const float s5 = 2.2360679774997896f;
            const float s15 = 3.8729833462074170f;
            const float s7 = 2.6457513110645907f;
            const float c33 = 2.0916500663351889f;
            const float c32 = 10.246950765959598f;
            const float c31 = 1.6201851746019651f;
            float* Yp = Ybuf + (size_t)ge * 16;
            Yp[0] = 1.f;
            Yp[1] = s3 * x;  Yp[2] = s3 * y;  Yp[3] = s3 * z;
            Yp[4] = s15 * x * y;  Yp[5] = s15 * y * z;
            Yp[6] = 0.5f * s5 * (3.f * z * z - 1.f);
            Yp[7] = s15 * x * z;
            Yp[8] = 0.5f * s15 * (x * x - y * y);
            Yp[9] = c33 * y * (3.f * x * x - y * y);
            Yp[10] = c32 * x * y * z;
            Yp[11] = c31 * y * (5.f * z * z - 1.f);
            Yp[12] = 0.5f * s7 * (5.f * z * z * z - 3.f * z);
            Yp[13] = c31 * x * (5.f * z * z - 1.f);
            Yp[14] = 0.5f * c32 * z * (x * x - y * y);
            Yp[15] = c33 * x * (x * x - 3.f * y * y);
        }
    }
    __syncthreads();

    // GEMM1: [64x64] @ [64x256]  (A=W frag, B=x frag); wave owns 32 cols
    f32x4 acc[4][2];
#pragma unroll
    for (int mt = 0; mt < 4; mt++)
#pragma unroll
        for (int nt = 0; nt < 2; nt++) acc[mt][nt] = (f32x4){0.f, 0.f, 0.f, 0.f};
#pragma unroll
    for (int kt = 0; kt < 2; kt++) {
        bf16x8 aw[2];
#pragma unroll
        for (int nt = 0; nt < 2; nt++)
            aw[nt] = *(const bf16x8*)(We0s + ((size_t)(kt * 256 + w * 32 + nt * 16 + lm) * 32 + lq * 8));
#pragma unroll
        for (int mt = 0; mt < 4; mt++) {
            bf16x8 bx = *(const bf16x8*)(As + (mt * 16 + lm) * LROW + kt * 32 + lq * 8);
#pragma unroll
            for (int nt = 0; nt < 2; nt++) acc[mt][nt] = MFMA_B16(aw[nt], bx, acc[mt][nt]);
        }
    }
    __syncthreads();   // all GEMM1 reads of As done before hidden overwrites it
    // y0 = silu(acc + b0) -> As cols 0..256 (feature region dead)
#pragma unroll
    for (int nt = 0; nt < 2; nt++) {
        int cb = w * 32 + nt * 16 + lq * 4;
        f32x4 bb = *(const f32x4*)(be0 + cb);
#pragma unroll
        for (int mt = 0; mt < 4; mt++) {
            int row = mt * 16 + lm;
            bf16x4 v = {f2bs(silu(acc[mt][nt][0] + bb[0])), f2bs(silu(acc[mt][nt][1] + bb[1])),
                        f2bs(silu(acc[mt][nt][2] + bb[2])), f2bs(silu(acc[mt][nt][3] + bb[3]))};
            *(bf16x4*)(As + row * LROW + cb) = v;
        }
    }
    __syncthreads();

    // GEMM2: [64x256] @ [256x256]  (hidden read back from As)
#pragma unroll
    for (int mt = 0; mt < 4; mt++)
#pragma unroll
        for (int nt = 0; nt < 2; nt++) acc[mt][nt] = (f32x4){0.f, 0.f, 0.f, 0.f};
#pragma unroll
    for (int kt = 0; kt < 8; kt++) {
        bf16x8 aw[2];
#pragma unroll
        for (int nt = 0; nt < 2; nt++)
            aw[nt] = *(const bf16x8*)(We1s + ((size_t)(kt * 256 + w * 32 + nt * 16 + lm) * 32 + lq * 8));
#pragma unroll
        for (int mt = 0; mt < 4; mt++) {
            bf16x8 bx = *(const bf16x8*)(As + (mt * 16 + lm) * LROW + kt * 32 + lq * 8);
#pragma unroll
            for (int nt = 0; nt < 2; nt++) acc[mt][nt] = MFMA_B16(aw[nt], bx, acc[mt][nt]);
        }
    }
    __syncthreads();   // all GEMM2 reads done before x1 overwrites As
    // epilogue: x1 = silu(.)*u -> xb global (NT stream-out) and As
#pragma unroll
    for (int nt = 0; nt < 2; nt++) {
        int cb = w * 32 + nt * 16 + lq * 4;
        f32x4 bb = *(const f32x4*)(be1 + cb);
#pragma unroll
        for (int mt = 0; mt < 4; mt++) {
            int row = mt * 16 + lm;
            float uu = us[row];
            bf16x4 v = {f2bs(silu(acc[mt][nt][0] + bb[0]) * uu),
                        f2bs(silu(acc[mt][nt][1] + bb[1]) * uu),
                        f2bs(silu(acc[mt][nt][2] + bb[2]) * uu),
                        f2bs(silu(acc[mt][nt][3] + bb[3]) * uu)};
            *(bf16x4*)(As + row * LROW + cb) = v;
            __builtin_nontemporal_store(v, (bf16x4*)(xb + (size_t)(eb + row) * H + cb));
        }
    }
    __syncthreads();

    // GEMM3: a = x@Wv0 (waves 0-3), w = x@Wlw0 (waves 4-7)
    if (w < 4) {
        f32x4 av = (f32x4){0.f, 0.f, 0.f, 0.f};
#pragma unroll
        for (int kt = 0; kt < 8; kt++) {
            bf16x8 bx = *(const bf16x8*)(As + (w * 16 + lm) * LROW + kt * 32 + lq * 8);
            bf16x8 a_v = *(const bf16x8*)(Wv0s + ((size_t)(kt * 16 + lm) * 32 + lq * 8));
            av = MFMA_B16(a_v, bx, av);
        }
        *(f32x4*)(abuf + (size_t)(eb + w * 16 + lm) * 16 + lq * 4) = av;
    } else {
        int w2 = w - 4;
        f32x4 aw2 = (f32x4){0.f, 0.f, 0.f, 0.f};
#pragma unroll
        for (int kt = 0; kt < 8; kt++) {
            bf16x8 bx = *(const bf16x8*)(As + (w2 * 16 + lm) * LROW + kt * 32 + lq * 8);
            bf16x8 a_w = *(const bf16x8*)(Wlws0 + ((size_t)(kt * 16 + lm) * 32 + lq * 8));
            aw2 = MFMA_B16(a_w, bx, aw2);
        }
        *(f32x4*)(wbuf + (size_t)(eb + w2 * 16 + lm) * 16 + lq * 4) = aw2;
    }
}

// ---------------- gather #1: wYn0 = inv*segsum(w ⊗ Y)  AND  vv0[e,m] =
// wYn0[s,m,0]*a[e,m]  (node-grouped: no per-edge wYn scatter later)
__global__ __launch_bounds__(256) void k_gather0(
    const int* __restrict__ off, const int* __restrict__ eidx,
    const float* __restrict__ wbuf, const float* __restrict__ Ybuf,
    const float* __restrict__ abuf,
    float* __restrict__ wYn0, __hip_bfloat16* __restrict__ vvbuf)
{
    __shared__ float ws[16][17];
    __shared__ float Ysh[16][17];
    __shared__ float Ash[16][17];
    __shared__ float w00[16];
    __shared__ int esh[16];
    int tid = threadIdx.x;
    int m = tid >> 4, i = tid & 15;
    for (int nn = 0; nn < 4; nn++) {
        int n = blockIdx.x * 4 + nn;
        int beg = off[n], end = off[n + 1];
        float acc = 0.f;
        for (int c = beg; c < end; c += 16) {
            int ne = min(16, end - c);
            if (m < ne) {
                int e = eidx[c + m];
                ws[m][i] = wbuf[(size_t)e * 16 + i];
                Ysh[m][i] = Ybuf[(size_t)e * 16 + i];
            }
            __syncthreads();
            for (int j2 = 0; j2 < ne; j2++) acc += ws[j2][m] * Ysh[j2][i];
            __syncthreads();
        }
        wYn0[(size_t)n * 256 + m * 16 + i] = acc * 0.25f;
        if (i == 0) w00[m] = acc * 0.25f;
        __syncthreads();
        // pass 2: vv0[e, col=i] = w00[i] * a[e, i]   (thread slot=m -> edge)
        for (int c = beg; c < end; c += 16) {
            int ne = min(16, end - c);
            if (m < ne) {
                int e = eidx[c + m];
                Ash[m][i] = abuf[(size_t)e * 16 + i];
                if (i == 0) esh[m] = e;
            }
            __syncthreads();
            if (m < ne)
                vvbuf[(size_t)esh[m] * 16 + i] = __float2bfloat16(w00[i] * Ash[m][i]);
            __syncthreads();
        }
    }
}

// ---------------- gather #2: wYn1 (local only) AND vv1[e,m] =
// wYn1[s,m,0]*a[e,m]*sum_i wYn0[s,m,i]*Wlsh0[i,0]*Y[e,i]
__global__ __launch_bounds__(256) void k_gather1(
    const int* __restrict__ off, const int* __restrict__ eidx,
    const float* __restrict__ wbuf, const float* __restrict__ Ybuf,
    const float* __restrict__ abuf,
    const float* __restrict__ wYn0, const float* __restrict__ Wlsh,
    __hip_bfloat16* __restrict__ vvbuf)
{
    __shared__ float ws[16][17];
    __shared__ float Ysh[16][17];
    __shared__ float Ash[16][17];
    __shared__ float qsh[16][17];
    __shared__ float w10[16];
    __shared__ int esh[16];
    int tid = threadIdx.x;
    int m = tid >> 4, i = tid & 15;
    for (int nn = 0; nn < 4; nn++) {
        int n = blockIdx.x * 4 + nn;
        int beg = off[n], end = off[n + 1];
        float acc = 0.f;
        for (int c = beg; c < end; c += 16) {
            int ne = min(16, end - c);
            if (m < ne) {
                int e = eidx[c + m];
                ws[m][i] = wbuf[(size_t)e * 16 + i];
                Ysh[m][i] = Ybuf[(size_t)e * 16 + i];
            }
            __syncthreads();
            for (int j2 = 0; j2 < ne; j2++) acc += ws[j2][m] * Ysh[j2][i];
            __syncthreads();
        }
        if (i == 0) w10[m] = acc * 0.25f;
        qsh[m][i] = wYn0[(size_t)n * 256 + m * 16 + i] * Wlsh[i * 16];
        __syncthreads();
        // pass 2: thread (slot=m -> edge, col=i): t = sum_i2 qsh[i][i2]*Y[e,i2]
        for (int c = beg; c < end; c += 16) {
            int ne = min(16, end - c);
            if (m < ne) {
                int e = eidx[c + m];
                Ysh[m][i] = Ybuf[(size_t)e * 16 + i];
                Ash[m][i] = abuf[(size_t)e * 16 + i];
                if (i == 0) esh[m] = e;
            }
            __syncthreads();
            if (m < ne) {
                float t = 0.f;
#pragma unroll
                for (int i2 = 0; i2 < 16; i2++) t += qsh[i][i2] * Ysh[m][i2];
                vvbuf[(size_t)esh[m] * 16 + i] = __float2bfloat16(w10[i] * Ash[m][i] * t);
            }
            __syncthreads();
        }
    }
}

// ---------------- MFMA layer tile kernel (operand-swapped, single buffer,
//                  x_old in registers, vv precomputed, NT stream-out)
__global__ __launch_bounds__(512, 6) void k_layer_mfma(
    __hip_bfloat16* __restrict__ xb, const float* __restrict__ ubuf,
    const __hip_bfloat16* __restrict__ vvbuf, const int* __restrict__ rcv,
    const __hip_bfloat16* __restrict__ W1s, const float* __restrict__ b1,
    const __hip_bfloat16* __restrict__ W2s, const float* __restrict__ b2,
    const __hip_bfloat16* __restrict__ Wlwn, float* __restrict__ wbufn,
    const __hip_bfloat16* __restrict__ Wouts, float* __restrict__ nacc,
    int layer)
{
    __shared__ __align__(16) __hip_bfloat16 As[64 * LROW];  // x|vv|0 -> hidden -> x_new
    int tid = threadIdx.x;
    int w = tid >> 6, l = tid & 63;
    int lm = l & 15, lq = l >> 4;
    int eb = blockIdx.x * 64;

    // stage x tile [64x256] -> As cols 0..256 (512 threads: 4 iters)
#pragma unroll
    for (int i = 0; i < 4; i++) {
        int c = tid + 512 * i;
        int row = c >> 5, kc = c & 31;
        *(bf16x8*)(As + row * LROW + kc * 8) =
            *(const bf16x8*)(xb + (size_t)(eb + row) * H + kc * 8);
    }
    // vv: coalesced 4B/thread from vvbuf; zeros 272..288
    {
        int el = tid & 63;
        int mh = (tid >> 6) * 2;     // 8 groups x 2 m each
        int ge = eb + el;
        *(unsigned int*)(As + el * LROW + 256 + mh) =
            *(const unsigned int*)((const short*)vvbuf + (size_t)ge * 16 + mh);
        if (tid < 64) {
#pragma unroll
            for (int j = 0; j < 16; j++) As[tid * LROW + 272 + j] = __float2bfloat16(0.f);
        }
    }
    __syncthreads();

    float uu[4];
#pragma unroll
    for (int mt = 0; mt < 4; mt++) uu[mt] = ubuf[eb + mt * 16 + lm];

    // x_old fragments -> registers (16 VGPR), survive GEMM1+GEMM2.
    bf16x4 xold[2][4];
#pragma unroll
    for (int nt = 0; nt < 2; nt++) {
        int cb = w * 32 + nt * 16 + lq * 4;
#pragma unroll
        for (int mt = 0; mt < 4; mt++)
            xold[nt][mt] = *(const bf16x4*)(As + (mt * 16 + lm) * LROW + cb);
    }

    // GEMM1: [64x288] @ [288x256]; wave owns 32 output cols
    f32x4 acc[4][2];
#pragma unroll
    for (int mt = 0; mt < 4; mt++)
#pragma unroll
        for (int nt = 0; nt < 2; nt++) acc[mt][nt] = (f32x4){0.f, 0.f, 0.f, 0.f};
#pragma unroll
    for (int kt = 0; kt < 9; kt++) {
        bf16x8 aw[2];
#pragma unroll
        for (int nt = 0; nt < 2; nt++)
            aw[nt] = *(const bf16x8*)(W1s + ((size_t)(kt * 256 + w * 32 + nt * 16 + lm) * 32 + lq * 8));
#pragma unroll
        for (int mt = 0; mt < 4; mt++) {
            bf16x8 bx = *(const bf16x8*)(As + (mt * 16 + lm) * LROW + kt * 32 + lq * 8);
#pragma unroll
            for (int nt = 0; nt < 2; nt++) acc[mt][nt] = MFMA_B16(aw[nt], bx, acc[mt][nt]);
        }
    }
    __syncthreads();   // all GEMM1 reads (and xold loads) done before overwrite
    // y1 = silu(acc + b1) -> As cols 0..256
#pragma unroll
    for (int nt = 0; nt < 2; nt++) {
        int cb = w * 32 + nt * 16 + lq * 4;
        f32x4 bb = *(const f32x4*)(b1 + cb);
#pragma unroll
        for (int mt = 0; mt < 4; mt++) {
            int row = mt * 16 + lm;
            bf16x4 v = {f2bs(silu(acc[mt][nt][0] + bb[0])), f2bs(silu(acc[mt][nt][1] + bb[1])),
                        f2bs(silu(acc[mt][nt][2] + bb[2])), f2bs(silu(acc[mt][nt][3] + bb[3]))};
            *(bf16x4*)(As + row * LROW + cb) = v;
        }
    }
    __syncthreads();

    // GEMM2: [64x256] @ [256x256]  (hidden read back from As)
#pragma unroll
    for (int mt = 0; mt < 4; mt++)
#pragma unroll
        for (int nt = 0; nt < 2; nt++) acc[mt][nt] = (f32x4){0.f, 0.f, 0.f, 0.f};
#pragma unroll
    for (int kt = 0; kt < 8; kt++) {
        bf16x8 aw[2];
#pragma unroll
        for (int nt = 0; nt < 2; nt++)
            aw[nt] = *(const bf16x8*)(W2s + ((size_t)(kt * 256 + w * 32 + nt * 16 + lm) * 32 + lq * 8));
#pragma unroll
        for (int mt = 0; mt < 4; mt++) {
            bf16x8 bx = *(const bf16x8*)(As + (mt * 16 + lm) * LROW + kt * 32 + lq * 8);
#pragma unroll
            for (int nt = 0; nt < 2; nt++) acc[mt][nt] = MFMA_B16(aw[nt], bx, acc[mt][nt]);
        }
    }
    __syncthreads();   // all GEMM2 reads done before x_new overwrites As
    // epilogue: xnew = (x_old + u*silu(acc+b2))/sqrt2; x_old from REGISTERS.
    const float rs2 = 0.70710678118654752f;
#pragma unroll
    for (int nt = 0; nt < 2; nt++) {
        int cb = w * 32 + nt * 16 + lq * 4;
        f32x4 bb = *(const f32x4*)(b2 + cb);
#pragma unroll
        for (int mt = 0; mt < 4; mt++) {
            int row = mt * 16 + lm;
            bf16x4 xo = xold[nt][mt];
            bf16x4 v;
#pragma unroll
            for (int r = 0; r < 4; r++) {
                float xn = (bs2f(xo[r]) + uu[mt] * silu(acc[mt][nt][r] + bb[r])) * rs2;
                v[r] = f2bs(xn);
            }
            *(bf16x4*)(As + row * LROW + cb) = v;
            if (layer == 0)
                __builtin_nontemporal_store(v, (bf16x4*)(xb + (size_t)(eb + row) * H + cb));
        }
    }
    __syncthreads();

    if (layer == 0) {
        // wcomp: w = x_new @ Wlwn -- waves 0-3 own edges w*16..w*16+15
        if (w < 4) {
            f32x4 cw = (f32x4){0.f, 0.f, 0.f, 0.f};
#pragma unroll
            for (int kt = 0; kt < 8; kt++) {
                bf16x8 bx = *(const bf16x8*)(As + (w * 16 + lm) * LROW + kt * 32 + lq * 8);
                bf16x8 a = *(const bf16x8*)(Wlwn + ((size_t)(kt * 16 + lm) * 32 + lq * 8));
                cw = MFMA_B16(a, bx, cw);
            }
            *(f32x4*)(wbufn + (size_t)(eb + w * 16 + lm) * 16 + lq * 4) = cw;
        }
    } else {
        // out-proj: edge_out = (x_new @ W_out) * u -> atomicAdd nacc[rcv]
        if (w < 4) {
            f32x4 co = (f32x4){0.f, 0.f, 0.f, 0.f};
#pragma unroll
            for (int kt = 0; kt < 8; kt++) {
                bf16x8 bx = *(const bf16x8*)(As + (w * 16 + lm) * LROW + kt * 32 + lq * 8);
                bf16x8 a = *(const bf16x8*)(Wouts + ((size_t)(kt * 16 + lm) * 32 + lq * 8));
                co = MFMA_B16(a, bx, co);
            }
            if (lq == 0) {
                int e = eb + w * 16 + lm;
                atomicAdd(&nacc[rcv[e]], co[0] * ubuf[e]);
            }
        }
    }
}

__global__ __launch_bounds__(256) void k_final(
    const float* __restrict__ nacc, void* __restrict__ out, const int* __restrict__ flag,
    float inv, int N)
{
    int n = blockIdx.x * 256 + threadIdx.x;
    if (n >= N) return;
    float v = nacc[n] * inv;
    if (*flag) ((float*)out)[n] = v;
    else       ((__hip_bfloat16*)out)[n] = __float2bfloat16(v);
}

extern "C" void kernel_launch(void* const* d_in, const int* in_sizes, int n_in,
                              void* d_out, int out_size, void* d_ws, size_t ws_size,
                              hipStream_t stream)
{
    const int E = in_sizes[2];      // 131072
    const int N = in_sizes[0] / F;  // 8192
    (void)n_in; (void)ws_size; (void)out_size;

    char* wsb = (char*)d_ws;
    size_t off = 0;
    int* flag = (int*)wsb; off += 256;

    const int fidx[14] = {0, 1, 4, 5, 6, 7, 8, 9, 10, 11, 12, 13, 14, 15};
    float* canon[14];
    for (int k = 0; k < 14; k++) {
        canon[k] = (float*)(wsb + off);
        off += (size_t)in_sizes[fidx[k]] * 4;
        off = (off + 255) & ~(size_t)255;
    }
    const float* naC   = canon[0];
    const float* vecC  = canon[1];
    const float* We0C  = canon[2];
    const float* be0C  = canon[3];
    const float* We1C  = canon[4];
    const float* be1C  = canon[5];
    const float* Wv0C  = canon[6];
    const float* WlwC  = canon[7];
    const float* WlshC = canon[8];
    const float* Wly1C = canon[9];
    const float* bly1C = canon[10];
    const float* Wly2C = canon[11];
    const float* bly2C = canon[12];
    const float* WoutC = canon[13];

    // swizzled bf16 weights
    __hip_bfloat16* We0s  = (__hip_bfloat16*)(wsb + off); off += 64 * 256 * 2;
    __hip_bfloat16* We1s  = (__hip_bfloat16*)(wsb + off); off += 256 * 256 * 2;
    __hip_bfloat16* Wv0s  = (__hip_bfloat16*)(wsb + off); off += 256 * 16 * 2;
    __hip_bfloat16* Wlws0 = (__hip_bfloat16*)(wsb + off); off += 256 * 16 * 2;
    __hip_bfloat16* Wlws1 = (__hip_bfloat16*)(wsb + off); off += 256 * 16 * 2;
    __hip_bfloat16* W1s0  = (__hip_bfloat16*)(wsb + off); off += 288 * 256 * 2;
    __hip_bfloat16* W1s1  = (__hip_bfloat16*)(wsb + off); off += 288 * 256 * 2;
    __hip_bfloat16* W2s0  = (__hip_bfloat16*)(wsb + off); off += 256 * 256 * 2;
    __hip_bfloat16* W2s1  = (__hip_bfloat16*)(wsb + off); off += 256 * 256 * 2;
    __hip_bfloat16* Wouts = (__hip_bfloat16*)(wsb + off); off += 256 * 16 * 2;
    off = (off + 255) & ~(size_t)255;

    __hip_bfloat16* xbuf = (__hip_bfloat16*)(wsb + off); off += (size_t)E * H * 2;
    float* wYn0 = (float*)(wsb + off); off += (size_t)N * H * 4;
    __hip_bfloat16* vvbuf = (__hip_bfloat16*)(wsb + off); off += (size_t)E * 16 * 2;
    float* ubuf = (float*)(wsb + off); off += (size_t)E * 4;
    float* Ybuf = (float*)(wsb + off); off += (size_t)E * 16 * 4;
    float* abuf = (float*)(wsb + off); off += (size_t)E * 16 * 4;
    float* wbuf = (float*)(wsb + off); off += (size_t)E * 16 * 4;
    float* nacc = (float*)(wsb + off); off += (size_t)N * 4;
    int* cnt  = (int*)(wsb + off); off += (size_t)N * 4;
    int* offb = (int*)(wsb + off); off += (size_t)(N + 1) * 4;
    int* cur  = (int*)(wsb + off); off += (size_t)N * 4;
    int* eidx = (int*)(wsb + off); off += (size_t)E * 4;

    const int* snd = (const int*)d_in[2];
    const int* rcv = (const int*)d_in[3];
    const float inv = 0.25f;
    const int nb64 = E / 64;

    // dtype sniff + merged canonicalization
    k_sniff<<<1, 256, 0, stream>>>(d_in[1], flag);
    {
        ConvArgs ca;
        int c = 0;
        for (int k = 0; k < 14; k++) {
            ca.src[k] = d_in[fidx[k]];
            ca.dst[k] = canon[k];
            ca.cum[k] = c;
            c += in_sizes[fidx[k]];
        }
        ca.cum[14] = c;
        k_conv_all<<<(c + 255) / 256, 256, 0, stream>>>(ca, flag);
    }

    // merged weight swizzles
    {
        SwzArgs sa;
        const float* srcs[9] = {We0C, We1C, Wv0C, WlwC, WlwC + 256 * 16,
                                Wly1C, Wly1C + 272 * 256, Wly2C, Wly2C + 256 * 256};
        __hip_bfloat16* dsts[9] = {We0s, We1s, Wv0s, Wlws0, Wlws1, W1s0, W1s1, W2s0, W2s1};
        int Ks[9]    = {40, 256, 256, 256, 256, 272, 272, 256, 256};
        int Ncs[9]   = {256, 256, 16, 16, 16, 256, 256, 256, 256};
        int Kpads[9] = {64, 256, 256, 256, 256, 288, 288, 256, 256};
        int c = 0;
        for (int j = 0; j < 9; j++) {
            sa.src[j] = srcs[j]; sa.dst[j] = dsts[j];
            sa.K[j] = Ks[j]; sa.Nc[j] = Ncs[j];
            sa.cum[j] = c;
            c += (Kpads[j] >> 5) * Ncs[j] * 32;
        }
        sa.cum[9] = c;
        k_swz_all<<<(c + 255) / 256, 256, 0, stream>>>(sa);
    }
    k_swz_wout<<<16, 256, 0, stream>>>(WoutC, Wouts);

    // sender CSR
    hipMemsetAsync(cnt, 0, (size_t)N * sizeof(int), stream);
    k_hist<<<(E + 255) / 256, 256, 0, stream>>>(snd, cnt, E);
    k_scan<<<1, 256, 0, stream>>>(cnt, offb, cur, N);
    k_cscatter<<<(E + 255) / 256, 256, 0, stream>>>(snd, cur, eidx, E);

    // embed (fused geometry)
    k_embed_mfma<<<nb64, 512, 0, stream>>>(vecC, naC, snd, rcv,
                                           We0s, be0C, We1s, be1C, Wv0s, Wlws0,
                                           ubuf, Ybuf, xbuf, abuf, wbuf);

    // layer 0: gather0 emits wYn0 + vv0; layer kernel emits w for layer 1
    k_gather0<<<N / 4, 256, 0, stream>>>(offb, eidx, wbuf, Ybuf, abuf, wYn0, vvbuf);
    k_layer_mfma<<<nb64, 512, 0, stream>>>(xbuf, ubuf, vvbuf, rcv,
                                           W1s0, bly1C, W2s0, bly2C,
                                           Wlws1, wbuf,
                                           (const __hip_bfloat16*)nullptr, (float*)nullptr, 0);
    // layer 1: gather1 emits vv1 (wYn1 kept local); fused out-proj -> nacc
    hipMemsetAsync(nacc, 0, (size_t)N * sizeof(float), stream);
    k_gather1<<<N / 4, 256, 0, stream>>>(offb, eidx, wbuf, Ybuf, abuf, wYn0, WlshC, vvbuf);
    k_layer_mfma<<<nb64, 512, 0, stream>>>(xbuf, ubuf, vvbuf, rcv,
                                           W1s1, bly1C + H, W2s1, bly2C + H,
                                           (const __hip_bfloat16*)nullptr, (float*)nullptr,
                                           Wouts, nacc, 1);

    k_final<<<(N + 255) / 256, 256, 0, stream>>>(nacc, d_out, flag, inv, N);
}

// Round 9
// 449.179 us; speedup vs baseline: 1.0503x; 1.0503x over previous
//
#include <hip/hip_runtime.h>
#include <hip/hip_bf16.h>
#include <math.h>

#define H 256
#define F 16
#define MUL 16
#define NB 8
#define LROW 296   // As row stride (elems): 148 dwords == 20 mod 32 -> 2-way (free)
#define YROW 264   // Ys row stride (elems): 132 dwords == 4 mod 32  -> 2-way (free)

typedef short bf16x8 __attribute__((ext_vector_type(8)));
typedef short bf16x4 __attribute__((ext_vector_type(4)));
typedef float f32x4 __attribute__((ext_vector_type(4)));
#define MFMA_B16(a, b, c) __builtin_amdgcn_mfma_f32_16x16x32_bf16(a, b, c, 0, 0, 0)

__device__ __forceinline__ float bf2f(__hip_bfloat16 x) { return __bfloat162float(x); }
__device__ __forceinline__ float silu(float x) { return x / (1.f + __expf(-x)); }
__device__ __forceinline__ short f2bs(float x)
{
    __hip_bfloat16 h = __float2bfloat16(x);
    short s; __builtin_memcpy(&s, &h, 2); return s;
}
__device__ __forceinline__ float bs2f(short s)
{
    __hip_bfloat16 h; __builtin_memcpy(&h, &s, 2); return __bfloat162float(h);
}

// ---------------- dtype sniffer: bf16 (flag=0) or fp32 (flag=1)?
__global__ __launch_bounds__(256) void k_sniff(const void* vec, int* flag)
{
    __shared__ int bad;
    int tid = threadIdx.x;
    if (tid == 0) bad = 0;
    __syncthreads();
    const __hip_bfloat16* hp = (const __hip_bfloat16*)vec;
    for (int i = tid; i < 1024; i += 256) {
        float f = bf2f(hp[i]);
        if (!(isfinite(f) && fabsf(f) <= 1.0f)) bad = 1;
    }
    __syncthreads();
    if (tid == 0) *flag = bad;
}

// ---------------- merged converter: 14 float inputs -> canonical fp32
struct ConvArgs {
    const void* src[14];
    float* dst[14];
    int cum[15];
};
__global__ __launch_bounds__(256) void k_conv_all(ConvArgs a, const int* __restrict__ flag)
{
    int gid = blockIdx.x * 256 + threadIdx.x;
    if (gid >= a.cum[14]) return;
    int k = 0;
    while (gid >= a.cum[k + 1]) k++;
    int i = gid - a.cum[k];
    float v = (*flag) ? ((const float*)a.src[k])[i]
                      : bf2f(((const __hip_bfloat16*)a.src[k])[i]);
    a.dst[k][i] = v;
}

// ---------------- merged weight swizzle: fp32 [K][N] -> bf16 frag-linear
struct SwzArgs {
    const float* src[9];
    __hip_bfloat16* dst[9];
    int K[9], Nc[9], cum[10];
};
__global__ __launch_bounds__(256) void k_swz_all(SwzArgs a)
{
    int gid = blockIdx.x * 256 + threadIdx.x;
    if (gid >= a.cum[9]) return;
    int j = 0;
    while (gid >= a.cum[j + 1]) j++;
    int idx = gid - a.cum[j];
    int kk = idx & 31;
    int n = (idx >> 5) % a.Nc[j];
    int kt = idx / (32 * a.Nc[j]);
    int k = kt * 32 + kk;
    float v = (k < a.K[j]) ? a.src[j][(size_t)k * a.Nc[j] + n] : 0.f;
    a.dst[j][idx] = __float2bfloat16(v);
}

// ---------------- W_out swizzle: [256][1] -> frag-linear [256x16], col 0 only
__global__ __launch_bounds__(256) void k_swz_wout(const float* __restrict__ Wout,
                                                  __hip_bfloat16* __restrict__ dst)
{
    int idx = blockIdx.x * 256 + threadIdx.x;   // 4096 total
    if (idx >= 8 * 16 * 32) return;
    int kk = idx & 31;
    int n = (idx >> 5) & 15;
    int kt = idx >> 9;
    float v = (n == 0) ? Wout[kt * 32 + kk] : 0.f;
    dst[idx] = __float2bfloat16(v);
}

// ---------------- CSR build
__global__ __launch_bounds__(256) void k_hist(const int* __restrict__ snd,
                                              int* __restrict__ cnt, int E)
{
    int e = blockIdx.x * 256 + threadIdx.x;
    if (e < E) atomicAdd(&cnt[snd[e]], 1);
}

__global__ __launch_bounds__(256) void k_scan(const int* __restrict__ cnt,
                                              int* __restrict__ off,
                                              int* __restrict__ cur, int N)
{
    __shared__ int sums[256];
    int tid = threadIdx.x;
    int chunk = (N + 255) / 256;
    int base = tid * chunk;
    int s = 0;
    for (int i = 0; i < chunk; i++) { int idx = base + i; if (idx < N) s += cnt[idx]; }
    sums[tid] = s;
    __syncthreads();
    for (int d = 1; d < 256; d <<= 1) {
        int v = (tid >= d) ? sums[tid - d] : 0;
        __syncthreads();
        sums[tid] += v;
        __syncthreads();
    }
    int run = (tid == 0) ? 0 : sums[tid - 1];
    for (int i = 0; i < chunk; i++) {
        int idx = base + i;
        if (idx < N) { off[idx] = run; cur[idx] = run; run += cnt[idx]; }
    }
    if (tid == 255) off[N] = run;
}

__global__ __launch_bounds__(256) void k_cscatter(const int* __restrict__ snd,
                                                  int* __restrict__ cur,
                                                  int* __restrict__ eidx, int E)
{
    int e = blockIdx.x * 256 + threadIdx.x;
    if (e >= E) return;
    int p = atomicAdd(&cur[snd[e]], 1);
    eidx[p] = e;
}

// =====================================================================
// Tile kernels (operand-swapped): A-operand = weight frag, B-operand = x frag
// Block = 64 edges x 16 waves (1024 thr). Waves split 2D: wave (wr,wc)
// owns rows wr*32..+32, cols wc*32..+32 (acc[2][2]) -> per-block LDS-read
// volume identical to the 8-wave version (each bx frag feeds 2 MFMAs).
// Dual LDS buffers (71680 B): 2 blocks/CU (L2-safe per r7/r8 traffic
// cliff: blocks/CU>2 write-amplifies 3-5x) but now 32 waves/CU = full
// thread occupancy. vv precomputed node-grouped (r5).
// =====================================================================

// ---------------- MFMA embed tile kernel with fused geometry prologue
__global__ __launch_bounds__(1024, 8) void k_embed_mfma(
    const float* __restrict__ vec, const float* __restrict__ na,
    const int* __restrict__ snd, const int* __restrict__ rcv,
    const __hip_bfloat16* __restrict__ We0s, const float* __restrict__ be0,
    const __hip_bfloat16* __restrict__ We1s, const float* __restrict__ be1,
    const __hip_bfloat16* __restrict__ Wv0s, const __hip_bfloat16* __restrict__ Wlws0,
    float* __restrict__ ubuf, float* __restrict__ Ybuf,
    __hip_bfloat16* __restrict__ xb, float* __restrict__ abuf,
    float* __restrict__ wbuf)
{
    __shared__ __align__(16) __hip_bfloat16 As[64 * LROW];  // 37888 B
    __shared__ __align__(16) __hip_bfloat16 Ys[64 * YROW];  // 33792 B
    __shared__ float us[64];
    int tid = threadIdx.x;
    int w = tid >> 6, l = tid & 63;
    int lm = l & 15, lq = l >> 4;
    int wr = w >> 3, wc = w & 7;   // 2 x 8 wave grid
    int eb = blockIdx.x * 64;

    // ---- fused geometry: features straight into As; u,Y to global ----
    {
        int el = tid & 63;
        int part = tid >> 6;       // 0..15; parts 0-5 used
        int ge = eb + el;
        const float SQ2 = 1.41421356237309515f;
        const float PI = 3.14159265358979323846f;
        if (part == 0) {
            float vx = vec[3 * ge + 0], vy = vec[3 * ge + 1], vz = vec[3 * ge + 2];
            float d = sqrtf(vx * vx + vy * vy + vz * vz);
            float d3 = d * d * d;
            float d6 = d3 * d3, d7 = d6 * d, d8 = d7 * d;
            float u = 1.f - 28.f * d6 + 48.f * d7 - 21.f * d8;
            u = (d < 1.f) ? u : 0.f;
            ubuf[ge] = u;
            us[el] = u;
            float invd = 1.f / d;
#pragma unroll
            for (int k = 1; k <= 4; k++)
                As[el * LROW + (k - 1)] = __float2bfloat16(SQ2 * sinf((float)k * PI * d) * invd);
        } else if (part == 4) {
            float vx = vec[3 * ge + 0], vy = vec[3 * ge + 1], vz = vec[3 * ge + 2];
            float d = sqrtf(vx * vx + vy * vy + vz * vz);
            float invd = 1.f / d;
#pragma unroll
            for (int k = 5; k <= 8; k++)
                As[el * LROW + (k - 1)] = __float2bfloat16(SQ2 * sinf((float)k * PI * d) * invd);
        } else if (part == 5) {
#pragma unroll
            for (int j = 40; j < 64; j++) As[el * LROW + j] = __float2bfloat16(0.f);
        } else if (part == 1) {
            int s = snd[ge];
#pragma unroll
            for (int j = 0; j < 16; j++)
                As[el * LROW + 8 + j] = __float2bfloat16(na[(size_t)s * F + j]);
        } else if (part == 2) {
            int r = rcv[ge];
#pragma unroll
            for (int j = 0; j < 16; j++)
                As[el * LROW + 24 + j] = __float2bfloat16(na[(size_t)r * F + j]);
        } else if (part == 3) {
            float vx = vec[3 * ge + 0], vy = vec[3 * ge + 1], vz = vec[3 * ge + 2];
            float d = sqrtf(vx * vx + vy * vy + vz * vz);
            float invd = 1.f / d;
            float x = vx * invd, y = vy * invd, z = vz * invd;
            const float s3 = 1.7320508075688772f;
            const float s5 = 2.2360679774997896f;
            const float s15 = 3.8729833462074170f;
            const float s7 = 2.6457513110645907f;
            const float c33 = 2.0916500663351889f;
            const float c32 = 10.246950765959598f;
            const float c31 = 1.6201851746019651f;
            float* Yp = Ybuf + (size_t)ge * 16;
            Yp[0] = 1.f;
            Yp[1] = s3 * x;  Yp[2] = s3 * y;  Yp[3] = s3 * z;
            Yp[4] = s15 * x * y;  Yp[5] = s15 * y * z;
            Yp[6] = 0.5f * s5 * (3.f * z * z - 1.f);
            Yp[7] = s15 * x * z;
            Yp[8] = 0.5f * s15 * (x * x - y * y);
            Yp[9] = c33 * y * (3.f * x * x - y * y);
            Yp[10] = c32 * x * y * z;
            Yp[11] = c31 * y * (5.f * z * z - 1.f);
            Yp[12] = 0.5f * s7 * (5.f * z * z * z - 3.f * z);
            Yp[13] = c31 * x * (5.f * z * z - 1.f);
            Yp[14] = 0.5f * c32 * z * (x * x - y * y);
            Yp[15] = c33 * x * (x * x - 3.f * y * y);
        }
    }
    __syncthreads();

    // GEMM1: [64x64] @ [64x256]; wave (wr,wc) owns rows wr*32+, cols wc*32+
    f32x4 acc[2][2];
#pragma unroll
    for (int mt = 0; mt < 2; mt++)
#pragma unroll
        for (int nt = 0; nt < 2; nt++) acc[mt][nt] = (f32x4){0.f, 0.f, 0.f, 0.f};
#pragma unroll
    for (int kt = 0; kt < 2; kt++) {
        bf16x8 aw[2];
#pragma unroll
        for (int nt = 0; nt < 2; nt++)
            aw[nt] = *(const bf16x8*)(We0s + ((size_t)(kt * 256 + wc * 32 + nt * 16 + lm) * 32 + lq * 8));
#pragma unroll
        for (int mt = 0; mt < 2; mt++) {
            bf16x8 bx = *(const bf16x8*)(As + (wr * 32 + mt * 16 + lm) * LROW + kt * 32 + lq * 8);
#pragma unroll
            for (int nt = 0; nt < 2; nt++) acc[mt][nt] = MFMA_B16(aw[nt], bx, acc[mt][nt]);
        }
    }
    // y0 = silu(acc + b0) -> Ys (disjoint from As: no barrier before writes)
#pragma unroll
    for (int nt = 0; nt < 2; nt++) {
        int cb = wc * 32 + nt * 16 + lq * 4;
        f32x4 bb = *(const f32x4*)(be0 + cb);
#pragma unroll
        for (int mt = 0; mt < 2; mt++) {
            int row = wr * 32 + mt * 16 + lm;
            bf16x4 v = {f2bs(silu(acc[mt][nt][0] + bb[0])), f2bs(silu(acc[mt][nt][1] + bb[1])),
                        f2bs(silu(acc[mt][nt][2] + bb[2])), f2bs(silu(acc[mt][nt][3] + bb[3]))};
            *(bf16x4*)(Ys + row * YROW + cb) = v;
        }
    }
    __syncthreads();

    // GEMM2: [64x256] @ [256x256]
#pragma unroll
    for (int mt = 0; mt < 2; mt++)
#pragma unroll
        for (int nt = 0; nt < 2; nt++) acc[mt][nt] = (f32x4){0.f, 0.f, 0.f, 0.f};
#pragma unroll
    for (int kt = 0; kt < 8; kt++) {
        bf16x8 aw[2];
#pragma unroll
        for (int nt = 0; nt < 2; nt++)
            aw[nt] = *(const bf16x8*)(We1s + ((size_t)(kt * 256 + wc * 32 + nt * 16 + lm) * 32 + lq * 8));
#pragma unroll
        for (int mt = 0; mt < 2; mt++) {
            bf16x8 bx = *(const bf16x8*)(Ys + (wr * 32 + mt * 16 + lm) * YROW + kt * 32 + lq * 8);
#pragma unroll
            for (int nt = 0; nt < 2; nt++) acc[mt][nt] = MFMA_B16(aw[nt], bx, acc[mt][nt]);
        }
    }
    // epilogue: x1 = silu(.)*u -> xb global and As
#pragma unroll
    for (int nt = 0; nt < 2; nt++) {
        int cb = wc * 32 + nt * 16 + lq * 4;
        f32x4 bb = *(const f32x4*)(be1 + cb);
#pragma unroll
        for (int mt = 0; mt < 2; mt++) {
            int row = wr * 32 + mt * 16 + lm;
            float uu = us[row];
            bf16x4 v = {f2bs(silu(acc[mt][nt][0] + bb[0]) * uu),
                        f2bs(silu(acc[mt][nt][1] + bb[1]) * uu),
                        f2bs(silu(acc[mt][nt][2] + bb[2]) * uu),
                        f2bs(silu(acc[mt][nt][3] + bb[3]) * uu)};
            *(bf16x4*)(As + row * LROW + cb) = v;
            *(bf16x4*)(xb + (size_t)(eb + row) * H + cb) = v;
        }
    }
    __syncthreads();

    // GEMM3: a = x@Wv0 (waves 0-3), w = x@Wlw0 (waves 4-7); 8-15 idle
    if (w < 4) {
        f32x4 av = (f32x4){0.f, 0.f, 0.f, 0.f};
#pragma unroll
        for (int kt = 0; kt < 8; kt++) {
            bf16x8 bx = *(const bf16x8*)(As + (w * 16 + lm) * LROW + kt * 32 + lq * 8);
            bf16x8 a_v = *(const bf16x8*)(Wv0s + ((size_t)(kt * 16 + lm) * 32 + lq * 8));
            av = MFMA_B16(a_v, bx, av);
        }
        *(f32x4*)(abuf + (size_t)(eb + w * 16 + lm) * 16 + lq * 4) = av;
    } else if (w < 8) {
        int w2 = w - 4;
        f32x4 aw2 = (f32x4){0.f, 0.f, 0.f, 0.f};
#pragma unroll
        for (int kt = 0; kt < 8; kt++) {
            bf16x8 bx = *(const bf16x8*)(As + (w2 * 16 + lm) * LROW + kt * 32 + lq * 8);
            bf16x8 a_w = *(const bf16x8*)(Wlws0 + ((size_t)(kt * 16 + lm) * 32 + lq * 8));
            aw2 = MFMA_B16(a_w, bx, aw2);
        }
        *(f32x4*)(wbuf + (size_t)(eb + w2 * 16 + lm) * 16 + lq * 4) = aw2;
    }
}

// ---------------- gather #1: wYn0 = inv*segsum(w ⊗ Y)  AND  vv0[e,m] =
// wYn0[s,m,0]*a[e,m]  (node-grouped: no per-edge wYn scatter later)
__global__ __launch_bounds__(256) void k_gather0(
    const int* __restrict__ off, const int* __restrict__ eidx,
    const float* __restrict__ wbuf, const float* __restrict__ Ybuf,
    const float* __restrict__ abuf,
    float* __restrict__ wYn0, __hip_bfloat16* __restrict__ vvbuf)
{
    __shared__ float ws[16][17];
    __shared__ float Ysh[16][17];
    __shared__ float Ash[16][17];
    __shared__ float w00[16];
    __shared__ int esh[16];
    int tid = threadIdx.x;
    int m = tid >> 4, i = tid & 15;
    for (int nn = 0; nn < 4; nn++) {
        int n = blockIdx.x * 4 + nn;
        int beg = off[n], end = off[n + 1];
        float acc = 0.f;
        for (int c = beg; c < end; c += 16) {
            int ne = min(16, end - c);
            if (m < ne) {
                int e = eidx[c + m];
                ws[m][i] = wbuf[(size_t)e * 16 + i];
                Ysh[m][i] = Ybuf[(size_t)e * 16 + i];
            }
            __syncthreads();
            for (int j2 = 0; j2 < ne; j2++) acc += ws[j2][m] * Ysh[j2][i];
            __syncthreads();
        }
        wYn0[(size_t)n * 256 + m * 16 + i] = acc * 0.25f;
        if (i == 0) w00[m] = acc * 0.25f;
        __syncthreads();
        // pass 2: vv0[e, col=i] = w00[i] * a[e, i]   (thread slot=m -> edge)
        for (int c = beg; c < end; c += 16) {
            int ne = min(16, end - c);
            if (m < ne) {
                int e = eidx[c + m];
                Ash[m][i] = abuf[(size_t)e * 16 + i];
                if (i == 0) esh[m] = e;
            }
            __syncthreads();
            if (m < ne)
                vvbuf[(size_t)esh[m] * 16 + i] = __float2bfloat16(w00[i] * Ash[m][i]);
            __syncthreads();
        }
    }
}

// ---------------- gather #2: wYn1 (local only) AND vv1[e,m] =
// wYn1[s,m,0]*a[e,m]*sum_i wYn0[s,m,i]*Wlsh0[i,0]*Y[e,i]
__global__ __launch_bounds__(256) void k_gather1(
    const int* __restrict__ off, const int* __restrict__ eidx,
    const float* __restrict__ wbuf, const float* __restrict__ Ybuf,
    const float* __restrict__ abuf,
    const float* __restrict__ wYn0, const float* __restrict__ Wlsh,
    __hip_bfloat16* __restrict__ vvbuf)
{
    __shared__ float ws[16][17];
    __shared__ float Ysh[16][17];
    __shared__ float Ash[16][17];
    __shared__ float qsh[16][17];
    __shared__ float w10[16];
    __shared__ int esh[16];
    int tid = threadIdx.x;
    int m = tid >> 4, i = tid & 15;
    for (int nn = 0; nn < 4; nn++) {
        int n = blockIdx.x * 4 + nn;
        int beg = off[n], end = off[n + 1];
        float acc = 0.f;
        for (int c = beg; c < end; c += 16) {
            int ne = min(16, end - c);
            if (m < ne) {
                int e = eidx[c + m];
                ws[m][i] = wbuf[(size_t)e * 16 + i];
                Ysh[m][i] = Ybuf[(size_t)e * 16 + i];
            }
            __syncthreads();
            for (int j2 = 0; j2 < ne; j2++) acc += ws[j2][m] * Ysh[j2][i];
            __syncthreads();
        }
        if (i == 0) w10[m] = acc * 0.25f;
        qsh[m][i] = wYn0[(size_t)n * 256 + m * 16 + i] * Wlsh[i * 16];
        __syncthreads();
        // pass 2: thread (slot=m -> edge, col=i): t = sum_i2 qsh[i][i2]*Y[e,i2]
        for (int c = beg; c < end; c += 16) {
            int ne = min(16, end - c);
            if (m < ne) {
                int e = eidx[c + m];
                Ysh[m][i] = Ybuf[(size_t)e * 16 + i];
                Ash[m][i] = abuf[(size_t)e * 16 + i];
                if (i == 0) esh[m] = e;
            }
            __syncthreads();
            if (m < ne) {
                float t = 0.f;
#pragma unroll
                for (int i2 = 0; i2 < 16; i2++) t += qsh[i][i2] * Ysh[m][i2];
                vvbuf[(size_t)esh[m] * 16 + i] = __float2bfloat16(w10[i] * Ash[m][i] * t);
            }
            __syncthreads();
        }
    }
}

// ---------------- MFMA layer tile kernel (operand-swapped, dual buffer,
//                  vv precomputed, 16 waves 2D-split)
__global__ __launch_bounds__(1024, 8) void k_layer_mfma(
    __hip_bfloat16* __restrict__ xb, const float* __restrict__ ubuf,
    const __hip_bfloat16* __restrict__ vvbuf, const int* __restrict__ rcv,
    const __hip_bfloat16* __restrict__ W1s, const float* __restrict__ b1,
    const __hip_bfloat16* __restrict__ W2s, const float* __restrict__ b2,
    const __hip_bfloat16* __restrict__ Wlwn, float* __restrict__ wbufn,
    const __hip_bfloat16* __restrict__ Wouts, float* __restrict__ nacc,
    int layer)
{
    __shared__ __align__(16) __hip_bfloat16 As[64 * LROW];  // x | vv | 0
    __shared__ __align__(16) __hip_bfloat16 Ys[64 * YROW];  // hidden
    int tid = threadIdx.x;
    int w = tid >> 6, l = tid & 63;
    int lm = l & 15, lq = l >> 4;
    int wr = w >> 3, wc = w & 7;   // 2 x 8 wave grid
    int eb = blockIdx.x * 64;

    // stage x tile [64x256] -> As cols 0..256 (1024 threads: 2 iters)
#pragma unroll
    for (int i = 0; i < 2; i++) {
        int c = tid + 1024 * i;
        int row = c >> 5, kc = c & 31;
        *(bf16x8*)(As + row * LROW + kc * 8) =
            *(const bf16x8*)(xb + (size_t)(eb + row) * H + kc * 8);
    }
    // vv: 2B/thread from vvbuf (16 groups x 1 m); zeros 272..288
    {
        int el = tid & 63;
        int m = tid >> 6;            // 0..15
        int ge = eb + el;
        As[el * LROW + 256 + m] = vvbuf[(size_t)ge * 16 + m];
        if (tid < 64) {
#pragma unroll
            for (int j = 0; j < 16; j++) As[tid * LROW + 272 + j] = __float2bfloat16(0.f);
        }
    }
    __syncthreads();

    float uu[2];
#pragma unroll
    for (int mt = 0; mt < 2; mt++) uu[mt] = ubuf[eb + wr * 32 + mt * 16 + lm];

    // GEMM1: [64x288] @ [288x256]; wave (wr,wc) owns rows wr*32+, cols wc*32+
    f32x4 acc[2][2];
#pragma unroll
    for (int mt = 0; mt < 2; mt++)
#pragma unroll
        for (int nt = 0; nt < 2; nt++) acc[mt][nt] = (f32x4){0.f, 0.f, 0.f, 0.f};
#pragma unroll
    for (int kt = 0; kt < 9; kt++) {
        bf16x8 aw[2];
#pragma unroll
        for (int nt = 0; nt < 2; nt++)
            aw[nt] = *(const bf16x8*)(W1s + ((size_t)(kt * 256 + wc * 32 + nt * 16 + lm) * 32 + lq * 8));
#pragma unroll
        for (int mt = 0; mt < 2; mt++) {
            bf16x8 bx = *(const bf16x8*)(As + (wr * 32 + mt * 16 + lm) * LROW + kt * 32 + lq * 8);
#pragma unroll
            for (int nt = 0; nt < 2; nt++) acc[mt][nt] = MFMA_B16(aw[nt], bx, acc[mt][nt]);
        }
    }
    // y1 = silu(acc + b1) -> Ys packed (disjoint from As)
#pragma unroll
    for (int nt = 0; nt < 2; nt++) {
        int cb = wc * 32 + nt * 16 + lq * 4;
        f32x4 bb = *(const f32x4*)(b1 + cb);
#pragma unroll
        for (int mt = 0; mt < 2; mt++) {
            int row = wr * 32 + mt * 16 + lm;
            bf16x4 v = {f2bs(silu(acc[mt][nt][0] + bb[0])), f2bs(silu(acc[mt][nt][1] + bb[1])),
                        f2bs(silu(acc[mt][nt][2] + bb[2])), f2bs(silu(acc[mt][nt][3] + bb[3]))};
            *(bf16x4*)(Ys + row * YROW + cb) = v;
        }
    }
    __syncthreads();

    // GEMM2: [64x256] @ [256x256]
#pragma unroll
    for (int mt = 0; mt < 2; mt++)
#pragma unroll
        for (int nt = 0; nt < 2; nt++) acc[mt][nt] = (f32x4){0.f, 0.f, 0.f, 0.f};
#pragma unroll
    for (int kt = 0; kt < 8; kt++) {
        bf16x8 aw[2];
#pragma unroll
        for (int nt = 0; nt < 2; nt++)
            aw[nt] = *(const bf16x8*)(W2s + ((size_t)(kt * 256 + wc * 32 + nt * 16 + lm) * 32 + lq * 8));
#pragma unroll
        for (int mt = 0; mt < 2; mt++) {
            bf16x8 bx = *(const bf16x8*)(Ys + (wr * 32 + mt * 16 + lm) * YROW + kt * 32 + lq * 8);
#pragma unroll
            for (int nt = 0; nt < 2; nt++) acc[mt][nt] = MFMA_B16(aw[nt], bx, acc[mt][nt]);
        }
    }
    // epilogue: xnew = (x_old + u*silu(acc+b2))/sqrt2; x_old read b64 from As;
    // same thread writes same cells (WAR-safe, no barrier).
    const float rs2 = 0.70710678118654752f;
#pragma unroll
    for (int nt = 0; nt < 2; nt++) {
        int cb = wc * 32 + nt * 16 + lq * 4;
        f32x4 bb = *(const f32x4*)(b2 + cb);
#pragma unroll
        for (int mt = 0; mt < 2; mt++) {
            int row = wr * 32 + mt * 16 + lm;
            bf16x4 xo = *(const bf16x4*)(As + row * LROW + cb);
            bf16x4 v;
#pragma unroll
            for (int r = 0; r < 4; r++) {
                float xn = (bs2f(xo[r]) + uu[mt] * silu(acc[mt][nt][r] + bb[r])) * rs2;
                v[r] = f2bs(xn);
            }
            *(bf16x4*)(As + row * LROW + cb) = v;
            if (layer == 0) *(bf16x4*)(xb + (size_t)(eb + row) * H + cb) = v;
        }
    }
    __syncthreads();

    if (layer == 0) {
        // wcomp: w = x_new @ Wlwn -- waves 0-3 own edges w*16..w*16+15
        if (w < 4) {
            f32x4 cw = (f32x4){0.f, 0.f, 0.f, 0.f};
#pragma unroll
            for (int kt = 0; kt < 8; kt++) {
                bf16x8 bx = *(const bf16x8*)(As + (w * 16 + lm) * LROW + kt * 32 + lq * 8);
                bf16x8 a = *(const bf16x8*)(Wlwn + ((size_t)(kt * 16 + lm) * 32 + lq * 8));
                cw = MFMA_B16(a, bx, cw);
            }
            *(f32x4*)(wbufn + (size_t)(eb + w * 16 + lm) * 16 + lq * 4) = cw;
        }
    } else {
        // out-proj: edge_out = (x_new @ W_out) * u -> atomicAdd nacc[rcv]
        if (w < 4) {
            f32x4 co = (f32x4){0.f, 0.f, 0.f, 0.f};
#pragma unroll
            for (int kt = 0; kt < 8; kt++) {
                bf16x8 bx = *(const bf16x8*)(As + (w * 16 + lm) * LROW + kt * 32 + lq * 8);
                bf16x8 a = *(const bf16x8*)(Wouts + ((size_t)(kt * 16 + lm) * 32 + lq * 8));
                co = MFMA_B16(a, bx, co);
            }
            if (lq == 0) {
                int e = eb + w * 16 + lm;
                atomicAdd(&nacc[rcv[e]], co[0] * ubuf[e]);
            }
        }
    }
}

__global__ __launch_bounds__(256) void k_final(
    const float* __restrict__ nacc, void* __restrict__ out, const int* __restrict__ flag,
    float inv, int N)
{
    int n = blockIdx.x * 256 + threadIdx.x;
    if (n >= N) return;
    float v = nacc[n] * inv;
    if (*flag) ((float*)out)[n] = v;
    else       ((__hip_bfloat16*)out)[n] = __float2bfloat16(v);
}

extern "C" void kernel_launch(void* const* d_in, const int* in_sizes, int n_in,
                              void* d_out, int out_size, void* d_ws, size_t ws_size,
                              hipStream_t stream)
{
    const int E = in_sizes[2];      // 131072
    const int N = in_sizes[0] / F;  // 8192
    (void)n_in; (void)ws_size; (void)out_size;

    char* wsb = (char*)d_ws;
    size_t off = 0;
    int* flag = (int*)wsb; off += 256;

    const int fidx[14] = {0, 1, 4, 5, 6, 7, 8, 9, 10, 11, 12, 13, 14, 15};
    float* canon[14];
    for (int k = 0; k < 14; k++) {
        canon[k] = (float*)(wsb + off);
        off += (size_t)in_sizes[fidx[k]] * 4;
        off = (off + 255) & ~(size_t)255;
    }
    const float* naC   = canon[0];
    const float* vecC  = canon[1];
    const float* We0C  = canon[2];
    const float* be0C  = canon[3];
    const float* We1C  = canon[4];
    const float* be1C  = canon[5];
    const float* Wv0C  = canon[6];
    const float* WlwC  = canon[7];
    const float* WlshC = canon[8];
    const float* Wly1C = canon[9];
    const float* bly1C = canon[10];
    const float* Wly2C = canon[11];
    const float* bly2C = canon[12];
    const float* WoutC = canon[13];

    // swizzled bf16 weights
    __hip_bfloat16* We0s  = (__hip_bfloat16*)(wsb + off); off += 64 * 256 * 2;
    __hip_bfloat16* We1s  = (__hip_bfloat16*)(wsb + off); off += 256 * 256 * 2;
    __hip_bfloat16* Wv0s  = (__hip_bfloat16*)(wsb + off); off += 256 * 16 * 2;
    __hip_bfloat16* Wlws0 = (__hip_bfloat16*)(wsb + off); off += 256 * 16 * 2;
    __hip_bfloat16* Wlws1 = (__hip_bfloat16*)(wsb + off); off += 256 * 16 * 2;
    __hip_bfloat16* W1s0  = (__hip_bfloat16*)(wsb + off); off += 288 * 256 * 2;
    __hip_bfloat16* W1s1  = (__hip_bfloat16*)(wsb + off); off += 288 * 256 * 2;
    __hip_bfloat16* W2s0  = (__hip_bfloat16*)(wsb + off); off += 256 * 256 * 2;
    __hip_bfloat16* W2s1  = (__hip_bfloat16*)(wsb + off); off += 256 * 256 * 2;
    __hip_bfloat16* Wouts = (__hip_bfloat16*)(wsb + off); off += 256 * 16 * 2;
    off = (off + 255) & ~(size_t)255;

    __hip_bfloat16* xbuf = (__hip_bfloat16*)(wsb + off); off += (size_t)E * H * 2;
    float* wYn0 = (float*)(wsb + off); off += (size_t)N * H * 4;
    __hip_bfloat16* vvbuf = (__hip_bfloat16*)(wsb + off); off += (size_t)E * 16 * 2;
    float* ubuf = (float*)(wsb + off); off += (size_t)E * 4;
    float* Ybuf = (float*)(wsb + off); off += (size_t)E * 16 * 4;
    float* abuf = (float*)(wsb + off); off += (size_t)E * 16 * 4;
    float* wbuf = (float*)(wsb + off); off += (size_t)E * 16 * 4;
    float* nacc = (float*)(wsb + off); off += (size_t)N * 4;
    int* cnt  = (int*)(wsb + off); off += (size_t)N * 4;
    int* offb = (int*)(wsb + off); off += (size_t)(N + 1) * 4;
    int* cur  = (int*)(wsb + off); off += (size_t)N * 4;
    int* eidx = (int*)(wsb + off); off += (size_t)E * 4;

    const int* snd = (const int*)d_in[2];
    const int* rcv = (const int*)d_in[3];
    const float inv = 0.25f;
    const int nb64 = E / 64;

    // dtype sniff + merged canonicalization
    k_sniff<<<1, 256, 0, stream>>>(d_in[1], flag);
    {
        ConvArgs ca;
        int c = 0;
        for (int k = 0; k < 14; k++) {
            ca.src[k] = d_in[fidx[k]];
            ca.dst[k] = canon[k];
            ca.cum[k] = c;
            c += in_sizes[fidx[k]];
        }
        ca.cum[14] = c;
        k_conv_all<<<(c + 255) / 256, 256, 0, stream>>>(ca, flag);
    }

    // merged weight swizzles
    {
        SwzArgs sa;
        const float* srcs[9] = {We0C, We1C, Wv0C, WlwC, WlwC + 256 * 16,
                                Wly1C, Wly1C + 272 * 256, Wly2C, Wly2C + 256 * 256};
        __hip_bfloat16* dsts[9] = {We0s, We1s, Wv0s, Wlws0, Wlws1, W1s0, W1s1, W2s0, W2s1};
        int Ks[9]    = {40, 256, 256, 256, 256, 272, 272, 256, 256};
        int Ncs[9]   = {256, 256, 16, 16, 16, 256, 256, 256, 256};
        int Kpads[9] = {64, 256, 256, 256, 256, 288, 288, 256, 256};
        int c = 0;
        for (int j = 0; j < 9; j++) {
            sa.src[j] = srcs[j]; sa.dst[j] = dsts[j];
            sa.K[j] = Ks[j]; sa.Nc[j] = Ncs[j];
            sa.cum[j] = c;
            c += (Kpads[j] >> 5) * Ncs[j] * 32;
        }
        sa.cum[9] = c;
        k_swz_all<<<(c + 255) / 256, 256, 0, stream>>>(sa);
    }
    k_swz_wout<<<16, 256, 0, stream>>>(WoutC, Wouts);

    // sender CSR
    hipMemsetAsync(cnt, 0, (size_t)N * sizeof(int), stream);
    k_hist<<<(E + 255) / 256, 256, 0, stream>>>(snd, cnt, E);
    k_scan<<<1, 256, 0, stream>>>(cnt, offb, cur, N);
    k_cscatter<<<(E + 255) / 256, 256, 0, stream>>>(snd, cur, eidx, E);

    // embed (fused geometry)
    k_embed_mfma<<<nb64, 1024, 0, stream>>>(vecC, naC, snd, rcv,
                                            We0s, be0C, We1s, be1C, Wv0s, Wlws0,
                                            ubuf, Ybuf, xbuf, abuf, wbuf);

    // layer 0: gather0 emits wYn0 + vv0; layer kernel emits w for layer 1
    k_gather0<<<N / 4, 256, 0, stream>>>(offb, eidx, wbuf, Ybuf, abuf, wYn0, vvbuf);
    k_layer_mfma<<<nb64, 1024, 0, stream>>>(xbuf, ubuf, vvbuf, rcv,
                                            W1s0, bly1C, W2s0, bly2C,
                                            Wlws1, wbuf,
                                            (const __hip_bfloat16*)nullptr, (float*)nullptr, 0);
    // layer 1: gather1 emits vv1 (wYn1 kept local); fused out-proj -> nacc
    hipMemsetAsync(nacc, 0, (size_t)N * sizeof(float), stream);
    k_gather1<<<N / 4, 256, 0, stream>>>(offb, eidx, wbuf, Ybuf, abuf, wYn0, WlshC, vvbuf);
    k_layer_mfma<<<nb64, 1024, 0, stream>>>(xbuf, ubuf, vvbuf, rcv,
                                            W1s1, bly1C + H, W2s1, bly2C + H,
                                            (const __hip_bfloat16*)nullptr, (float*)nullptr,
                                            Wouts, nacc, 1);

    k_final<<<(N + 255) / 256, 256, 0, stream>>>(nacc, d_out, flag, inv, N);
}

// Round 10
// 360.438 us; speedup vs baseline: 1.3089x; 1.2462x over previous
//
#include <hip/hip_runtime.h>
#include <hip/hip_bf16.h>
#include <math.h>

#define H 256
#define F 16
#define MUL 16
#define NB 8
#define LROW 296   // As row stride (elems): 148 dwords == 20 mod 32 -> 2-way (free)
#define YROW 264   // Ys row stride (elems): 132 dwords == 4 mod 32  -> 2-way (free)

typedef short bf16x8 __attribute__((ext_vector_type(8)));
typedef short bf16x4 __attribute__((ext_vector_type(4)));
typedef float f32x4 __attribute__((ext_vector_type(4)));
#define MFMA_B16(a, b, c) __builtin_amdgcn_mfma_f32_16x16x32_bf16(a, b, c, 0, 0, 0)

__device__ __forceinline__ float bf2f(__hip_bfloat16 x) { return __bfloat162float(x); }
// silu via v_rcp (no -ffast-math: plain '/' emits the full div-fixup chain)
__device__ __forceinline__ float silu(float x)
{
    return x * __builtin_amdgcn_rcpf(1.f + __expf(-x));
}
__device__ __forceinline__ short f2bs(float x)
{
    __hip_bfloat16 h = __float2bfloat16(x);
    short s; __builtin_memcpy(&s, &h, 2); return s;
}
__device__ __forceinline__ float bs2f(short s)
{
    __hip_bfloat16 h; __builtin_memcpy(&h, &s, 2); return __bfloat162float(h);
}

// ---------------- dtype sniffer: bf16 (flag=0) or fp32 (flag=1)?
__global__ __launch_bounds__(256) void k_sniff(const void* vec, int* flag)
{
    __shared__ int bad;
    int tid = threadIdx.x;
    if (tid == 0) bad = 0;
    __syncthreads();
    const __hip_bfloat16* hp = (const __hip_bfloat16*)vec;
    for (int i = tid; i < 1024; i += 256) {
        float f = bf2f(hp[i]);
        if (!(isfinite(f) && fabsf(f) <= 1.0f)) bad = 1;
    }
    __syncthreads();
    if (tid == 0) *flag = bad;
}

// ---------------- merged converter: 14 float inputs -> canonical fp32
struct ConvArgs {
    const void* src[14];
    float* dst[14];
    int cum[15];
};
__global__ __launch_bounds__(256) void k_conv_all(ConvArgs a, const int* __restrict__ flag)
{
    int gid = blockIdx.x * 256 + threadIdx.x;
    if (gid >= a.cum[14]) return;
    int k = 0;
    while (gid >= a.cum[k + 1]) k++;
    int i = gid - a.cum[k];
    float v = (*flag) ? ((const float*)a.src[k])[i]
                      : bf2f(((const __hip_bfloat16*)a.src[k])[i]);
    a.dst[k][i] = v;
}

// ---------------- merged weight swizzle: fp32 [K][N] -> bf16 frag-linear
struct SwzArgs {
    const float* src[9];
    __hip_bfloat16* dst[9];
    int K[9], Nc[9], cum[10];
};
__global__ __launch_bounds__(256) void k_swz_all(SwzArgs a)
{
    int gid = blockIdx.x * 256 + threadIdx.x;
    if (gid >= a.cum[9]) return;
    int j = 0;
    while (gid >= a.cum[j + 1]) j++;
    int idx = gid - a.cum[j];
    int kk = idx & 31;
    int n = (idx >> 5) % a.Nc[j];
    int kt = idx / (32 * a.Nc[j]);
    int k = kt * 32 + kk;
    float v = (k < a.K[j]) ? a.src[j][(size_t)k * a.Nc[j] + n] : 0.f;
    a.dst[j][idx] = __float2bfloat16(v);
}

// ---------------- W_out swizzle: [256][1] -> frag-linear [256x16], col 0 only
__global__ __launch_bounds__(256) void k_swz_wout(const float* __restrict__ Wout,
                                                  __hip_bfloat16* __restrict__ dst)
{
    int idx = blockIdx.x * 256 + threadIdx.x;   // 4096 total
    if (idx >= 8 * 16 * 32) return;
    int kk = idx & 31;
    int n = (idx >> 5) & 15;
    int kt = idx >> 9;
    float v = (n == 0) ? Wout[kt * 32 + kk] : 0.f;
    dst[idx] = __float2bfloat16(v);
}

// ---------------- CSR build
__global__ __launch_bounds__(256) void k_hist(const int* __restrict__ snd,
                                              int* __restrict__ cnt, int E)
{
    int e = blockIdx.x * 256 + threadIdx.x;
    if (e < E) atomicAdd(&cnt[snd[e]], 1);
}

__global__ __launch_bounds__(256) void k_scan(const int* __restrict__ cnt,
                                              int* __restrict__ off,
                                              int* __restrict__ cur, int N)
{
    __shared__ int sums[256];
    int tid = threadIdx.x;
    int chunk = (N + 255) / 256;
    int base = tid * chunk;
    int s = 0;
    for (int i = 0; i < chunk; i++) { int idx = base + i; if (idx < N) s += cnt[idx]; }
    sums[tid] = s;
    __syncthreads();
    for (int d = 1; d < 256; d <<= 1) {
        int v = (tid >= d) ? sums[tid - d] : 0;
        __syncthreads();
        sums[tid] += v;
        __syncthreads();
    }
    int run = (tid == 0) ? 0 : sums[tid - 1];
    for (int i = 0; i < chunk; i++) {
        int idx = base + i;
        if (idx < N) { off[idx] = run; cur[idx] = run; run += cnt[idx]; }
    }
    if (tid == 255) off[N] = run;
}

__global__ __launch_bounds__(256) void k_cscatter(const int* __restrict__ snd,
                                                  int* __restrict__ cur,
                                                  int* __restrict__ eidx, int E)
{
    int e = blockIdx.x * 256 + threadIdx.x;
    if (e >= E) return;
    int p = atomicAdd(&cur[snd[e]], 1);
    eidx[p] = e;
}

// =====================================================================
// Tile kernels (operand-swapped): A-operand = weight frag, B-operand = x frag
// Block = 64 edges x 8 waves (512 thr); wave w owns outcol slice 32w..32w+31.
// Dual LDS buffers (71680 B) -> 2 blocks/CU, 16 waves/CU. This is the
// measured structural optimum: blocks/CU>2 write-amplifies (L2 dirty-line
// cliff, r7/r8); 16 thin waves regress (r9: per-wave ILP loss beats
// occupancy gain). vv precomputed node-grouped (r5). This round: cut VALU
// (silu-div -> v_rcp, sinf -> v_sin) -- no-fast-math made those chains.
// =====================================================================

// ---------------- MFMA embed tile kernel with fused geometry prologue
__global__ __launch_bounds__(512, 4) void k_embed_mfma(
    const float* __restrict__ vec, const float* __restrict__ na,
    const int* __restrict__ snd, const int* __restrict__ rcv,
    const __hip_bfloat16* __restrict__ We0s, const float* __restrict__ be0,
    const __hip_bfloat16* __restrict__ We1s, const float* __restrict__ be1,
    const __hip_bfloat16* __restrict__ Wv0s, const __hip_bfloat16* __restrict__ Wlws0,
    float* __restrict__ ubuf, float* __restrict__ Ybuf,
    __hip_bfloat16* __restrict__ xb, float* __restrict__ abuf,
    float* __restrict__ wbuf)
{
    __shared__ __align__(16) __hip_bfloat16 As[64 * LROW];  // 37888 B
    __shared__ __align__(16) __hip_bfloat16 Ys[64 * YROW];  // 33792 B
    __shared__ float us[64];
    int tid = threadIdx.x;
    int w = tid >> 6, l = tid & 63;
    int lm = l & 15, lq = l >> 4;
    int eb = blockIdx.x * 64;

    // ---- fused geometry: features straight into As; u,Y to global ----
    {
        int el = tid & 63;
        int part = tid >> 6;
        int ge = eb + el;
        const float SQ2 = 1.41421356237309515f;
        const float PI = 3.14159265358979323846f;
        if (part == 0) {
            float vx = vec[3 * ge + 0], vy = vec[3 * ge + 1], vz = vec[3 * ge + 2];
            float d = sqrtf(vx * vx + vy * vy + vz * vz);
            float d3 = d * d * d;
            float d6 = d3 * d3, d7 = d6 * d, d8 = d7 * d;
            float u = 1.f - 28.f * d6 + 48.f * d7 - 21.f * d8;
            u = (d < 1.f) ? u : 0.f;
            ubuf[ge] = u;
            us[el] = u;
            float invd = __builtin_amdgcn_rcpf(d);
#pragma unroll
            for (int k = 1; k <= 4; k++)
                As[el * LROW + (k - 1)] = __float2bfloat16(SQ2 * __sinf((float)k * PI * d) * invd);
        } else if (part == 4) {
            float vx = vec[3 * ge + 0], vy = vec[3 * ge + 1], vz = vec[3 * ge + 2];
            float d = sqrtf(vx * vx + vy * vy + vz * vz);
            float invd = __builtin_amdgcn_rcpf(d);
#pragma unroll
            for (int k = 5; k <= 8; k++)
                As[el * LROW + (k - 1)] = __float2bfloat16(SQ2 * __sinf((float)k * PI * d) * invd);
        } else if (part == 5) {
#pragma unroll
            for (int j = 40; j < 64; j++) As[el * LROW + j] = __float2bfloat16(0.f);
        } else if (part == 1) {
            int s = snd[ge];
#pragma unroll
            for (int j = 0; j < 16; j++)
                As[el * LROW + 8 + j] = __float2bfloat16(na[(size_t)s * F + j]);
        } else if (part == 2) {
            int r = rcv[ge];
#pragma unroll
            for (int j = 0; j < 16; j++)
                As[el * LROW + 24 + j] = __float2bfloat16(na[(size_t)r * F + j]);
        } else if (part == 3) {
            float vx = vec[3 * ge + 0], vy = vec[3 * ge + 1], vz = vec[3 * ge + 2];
            float d = sqrtf(vx * vx + vy * vy + vz * vz);
            float invd = __builtin_amdgcn_rcpf(d);
            float x = vx * invd, y = vy * invd, z = vz * invd;
            const float s3 = 1.7320508075688772f;
            const float s5 = 2.2360679774997896f;
            const float s15 = 3.8729833462074170f;
            const float s7 = 2.6457513110645907f;
            const float c33 = 2.0916500663351889f;
            const float c32 = 10.246950765959598f;
            const float c31 = 1.6201851746019651f;
            float* Yp = Ybuf + (size_t)ge * 16;
            Yp[0] = 1.f;
            Yp[1] = s3 * x;  Yp[2] = s3 * y;  Yp[3] = s3 * z;
            Yp[4] = s15 * x * y;  Yp[5] = s15 * y * z;
            Yp[6] = 0.5f * s5 * (3.f * z * z - 1.f);
            Yp[7] = s15 * x * z;
            Yp[8] = 0.5f * s15 * (x * x - y * y);
            Yp[9] = c33 * y * (3.f * x * x - y * y);
            Yp[10] = c32 * x * y * z;
            Yp[11] = c31 * y * (5.f * z * z - 1.f);
            Yp[12] = 0.5f * s7 * (5.f * z * z * z - 3.f * z);
            Yp[13] = c31 * x * (5.f * z * z - 1.f);
            Yp[14] = 0.5f * c32 * z * (x * x - y * y);
            Yp[15] = c33 * x * (x * x - 3.f * y * y);
        }
    }
    __syncthreads();

    // GEMM1: [64x64] @ [64x256]  (A=W frag, B=x frag); wave owns 32 cols
    f32x4 acc[4][2];
#pragma unroll
    for (int mt = 0; mt < 4; mt++)
#pragma unroll
        for (int nt = 0; nt < 2; nt++) acc[mt][nt] = (f32x4){0.f, 0.f, 0.f, 0.f};
#pragma unroll
    for (int kt = 0; kt < 2; kt++) {
        bf16x8 aw[2];
#pragma unroll
        for (int nt = 0; nt < 2; nt++)
            aw[nt] = *(const bf16x8*)(We0s + ((size_t)(kt * 256 + w * 32 + nt * 16 + lm) * 32 + lq * 8));
#pragma unroll
        for (int mt = 0; mt < 4; mt++) {
            bf16x8 bx = *(const bf16x8*)(As + (mt * 16 + lm) * LROW + kt * 32 + lq * 8);
#pragma unroll
            for (int nt = 0; nt < 2; nt++) acc[mt][nt] = MFMA_B16(aw[nt], bx, acc[mt][nt]);
        }
    }
    // y0 = silu(acc + b0) -> Ys (disjoint from As: no barrier before writes)
#pragma unroll
    for (int nt = 0; nt < 2; nt++) {
        int cb = w * 32 + nt * 16 + lq * 4;
        f32x4 bb = *(const f32x4*)(be0 + cb);
#pragma unroll
        for (int mt = 0; mt < 4; mt++) {
            int row = mt * 16 + lm;
            bf16x4 v = {f2bs(silu(acc[mt][nt][0] + bb[0])), f2bs(silu(acc[mt][nt][1] + bb[1])),
                        f2bs(silu(acc[mt][nt][2] + bb[2])), f2bs(silu(acc[mt][nt][3] + bb[3]))};
            *(bf16x4*)(Ys + row * YROW + cb) = v;
        }
    }
    __syncthreads();

    // GEMM2: [64x256] @ [256x256]
#pragma unroll
    for (int mt = 0; mt < 4; mt++)
#pragma unroll
        for (int nt = 0; nt < 2; nt++) acc[mt][nt] = (f32x4){0.f, 0.f, 0.f, 0.f};
#pragma unroll
    for (int kt = 0; kt < 8; kt++) {
        bf16x8 aw[2];
#pragma unroll
        for (int nt = 0; nt < 2; nt++)
            aw[nt] = *(const bf16x8*)(We1s + ((size_t)(kt * 256 + w * 32 + nt * 16 + lm) * 32 + lq * 8));
#pragma unroll
        for (int mt = 0; mt < 4; mt++) {
            bf16x8 bx = *(const bf16x8*)(Ys + (mt * 16 + lm) * YROW + kt * 32 + lq * 8);
#pragma unroll
            for (int nt = 0; nt < 2; nt++) acc[mt][nt] = MFMA_B16(aw[nt], bx, acc[mt][nt]);
        }
    }
    // epilogue: x1 = silu(.)*u -> xb global (8B stores) and As
#pragma unroll
    for (int nt = 0; nt < 2; nt++) {
        int cb = w * 32 + nt * 16 + lq * 4;
        f32x4 bb = *(const f32x4*)(be1 + cb);
#pragma unroll
        for (int mt = 0; mt < 4; mt++) {
            int row = mt * 16 + lm;
            float uu = us[row];
            bf16x4 v = {f2bs(silu(acc[mt][nt][0] + bb[0]) * uu),
                        f2bs(silu(acc[mt][nt][1] + bb[1]) * uu),
                        f2bs(silu(acc[mt][nt][2] + bb[2]) * uu),
                        f2bs(silu(acc[mt][nt][3] + bb[3]) * uu)};
            *(bf16x4*)(As + row * LROW + cb) = v;
            *(bf16x4*)(xb + (size_t)(eb + row) * H + cb) = v;
        }
    }
    __syncthreads();

    // GEMM3: a = x@Wv0 (waves 0-3), w = x@Wlw0 (waves 4-7)
    if (w < 4) {
        f32x4 av = (f32x4){0.f, 0.f, 0.f, 0.f};
#pragma unroll
        for (int kt = 0; kt < 8; kt++) {
            bf16x8 bx = *(const bf16x8*)(As + (w * 16 + lm) * LROW + kt * 32 + lq * 8);
            bf16x8 a_v = *(const bf16x8*)(Wv0s + ((size_t)(kt * 16 + lm) * 32 + lq * 8));
            av = MFMA_B16(a_v, bx, av);
        }
        *(f32x4*)(abuf + (size_t)(eb + w * 16 + lm) * 16 + lq * 4) = av;
    } else {
        int w2 = w - 4;
        f32x4 aw2 = (f32x4){0.f, 0.f, 0.f, 0.f};
#pragma unroll
        for (int kt = 0; kt < 8; kt++) {
            bf16x8 bx = *(const bf16x8*)(As + (w2 * 16 + lm) * LROW + kt * 32 + lq * 8);
            bf16x8 a_w = *(const bf16x8*)(Wlws0 + ((size_t)(kt * 16 + lm) * 32 + lq * 8));
            aw2 = MFMA_B16(a_w, bx, aw2);
        }
        *(f32x4*)(wbuf + (size_t)(eb + w2 * 16 + lm) * 16 + lq * 4) = aw2;
    }
}

// ---------------- gather #1: wYn0 = inv*segsum(w ⊗ Y)  AND  vv0[e,m] =
// wYn0[s,m,0]*a[e,m]  (node-grouped: no per-edge wYn scatter later)
__global__ __launch_bounds__(256) void k_gather0(
    const int* __restrict__ off, const int* __restrict__ eidx,
    const float* __restrict__ wbuf, const float* __restrict__ Ybuf,
    const float* __restrict__ abuf,
    float* __restrict__ wYn0, __hip_bfloat16* __restrict__ vvbuf)
{
    __shared__ float ws[16][17];
    __shared__ float Ysh[16][17];
    __shared__ float Ash[16][17];
    __shared__ float w00[16];
    __shared__ int esh[16];
    int tid = threadIdx.x;
    int m = tid >> 4, i = tid & 15;
    for (int nn = 0; nn < 4; nn++) {
        int n = blockIdx.x * 4 + nn;
        int beg = off[n], end = off[n + 1];
        float acc = 0.f;
        for (int c = beg; c < end; c += 16) {
            int ne = min(16, end - c);
            if (m < ne) {
                int e = eidx[c + m];
                ws[m][i] = wbuf[(size_t)e * 16 + i];
                Ysh[m][i] = Ybuf[(size_t)e * 16 + i];
            }
            __syncthreads();
            for (int j2 = 0; j2 < ne; j2++) acc += ws[j2][m] * Ysh[j2][i];
            __syncthreads();
        }
        wYn0[(size_t)n * 256 + m * 16 + i] = acc * 0.25f;
        if (i == 0) w00[m] = acc * 0.25f;
        __syncthreads();
        // pass 2: vv0[e, col=i] = w00[i] * a[e, i]   (thread slot=m -> edge)
        for (int c = beg; c < end; c += 16) {
            int ne = min(16, end - c);
            if (m < ne) {
                int e = eidx[c + m];
                Ash[m][i] = abuf[(size_t)e * 16 + i];
                if (i == 0) esh[m] = e;
            }
            __syncthreads();
            if (m < ne)
                vvbuf[(size_t)esh[m] * 16 + i] = __float2bfloat16(w00[i] * Ash[m][i]);
            __syncthreads();
        }
    }
}

// ---------------- gather #2: wYn1 (local only) AND vv1[e,m] =
// wYn1[s,m,0]*a[e,m]*sum_i wYn0[s,m,i]*Wlsh0[i,0]*Y[e,i]
__global__ __launch_bounds__(256) void k_gather1(
    const int* __restrict__ off, const int* __restrict__ eidx,
    const float* __restrict__ wbuf, const float* __restrict__ Ybuf,
    const float* __restrict__ abuf,
    const float* __restrict__ wYn0, const float* __restrict__ Wlsh,
    __hip_bfloat16* __restrict__ vvbuf)
{
    __shared__ float ws[16][17];
    __shared__ float Ysh[16][17];
    __shared__ float Ash[16][17];
    __shared__ float qsh[16][17];
    __shared__ float w10[16];
    __shared__ int esh[16];
    int tid = threadIdx.x;
    int m = tid >> 4, i = tid & 15;
    for (int nn = 0; nn < 4; nn++) {
        int n = blockIdx.x * 4 + nn;
        int beg = off[n], end = off[n + 1];
        float acc = 0.f;
        for (int c = beg; c < end; c += 16) {
            int ne = min(16, end - c);
            if (m < ne) {
                int e = eidx[c + m];
                ws[m][i] = wbuf[(size_t)e * 16 + i];
                Ysh[m][i] = Ybuf[(size_t)e * 16 + i];
            }
            __syncthreads();
            for (int j2 = 0; j2 < ne; j2++) acc += ws[j2][m] * Ysh[j2][i];
            __syncthreads();
        }
        if (i == 0) w10[m] = acc * 0.25f;
        qsh[m][i] = wYn0[(size_t)n * 256 + m * 16 + i] * Wlsh[i * 16];
        __syncthreads();
        // pass 2: thread (slot=m -> edge, col=i): t = sum_i2 qsh[i][i2]*Y[e,i2]
        for (int c = beg; c < end; c += 16) {
            int ne = min(16, end - c);
            if (m < ne) {
                int e = eidx[c + m];
                Ysh[m][i] = Ybuf[(size_t)e * 16 + i];
                Ash[m][i] = abuf[(size_t)e * 16 + i];
                if (i == 0) esh[m] = e;
            }
            __syncthreads();
            if (m < ne) {
                float t = 0.f;
#pragma unroll
                for (int i2 = 0; i2 < 16; i2++) t += qsh[i][i2] * Ysh[m][i2];
                vvbuf[(size_t)esh[m] * 16 + i] = __float2bfloat16(w10[i] * Ash[m][i] * t);
            }
            __syncthreads();
        }
    }
}

// ---------------- MFMA layer tile kernel (operand-swapped, dual buffer,
//                  vv precomputed -> linear coalesced prologue)
__global__ __launch_bounds__(512, 4) void k_layer_mfma(
    __hip_bfloat16* __restrict__ xb, const float* __restrict__ ubuf,
    const __hip_bfloat16* __restrict__ vvbuf, const int* __restrict__ rcv,
    const __hip_bfloat16* __restrict__ W1s, const float* __restrict__ b1,
    const __hip_bfloat16* __restrict__ W2s, const float* __restrict__ b2,
    const __hip_bfloat16* __restrict__ Wlwn, float* __restrict__ wbufn,
    const __hip_bfloat16* __restrict__ Wouts, float* __restrict__ nacc,
    int layer)
{
    __shared__ __align__(16) __hip_bfloat16 As[64 * LROW];  // x | vv | 0
    __shared__ __align__(16) __hip_bfloat16 Ys[64 * YROW];  // hidden
    int tid = threadIdx.x;
    int w = tid >> 6, l = tid & 63;
    int lm = l & 15, lq = l >> 4;
    int eb = blockIdx.x * 64;

    // stage x tile [64x256] -> As cols 0..256 (512 threads: 4 iters)
#pragma unroll
    for (int i = 0; i < 4; i++) {
        int c = tid + 512 * i;
        int row = c >> 5, kc = c & 31;
        *(bf16x8*)(As + row * LROW + kc * 8) =
            *(const bf16x8*)(xb + (size_t)(eb + row) * H + kc * 8);
    }
    // vv: coalesced 4B/thread from vvbuf; zeros 272..288
    {
        int el = tid & 63;
        int mh = (tid >> 6) * 2;     // 8 groups x 2 m each
        int ge = eb + el;
        *(unsigned int*)(As + el * LROW + 256 + mh) =
            *(const unsigned int*)((const short*)vvbuf + (size_t)ge * 16 + mh);
        if (tid < 64) {
#pragma unroll
            for (int j = 0; j < 16; j++) As[tid * LROW + 272 + j] = __float2bfloat16(0.f);
        }
    }
    __syncthreads();

    float uu[4];
#pragma unroll
    for (int mt = 0; mt < 4; mt++) uu[mt] = ubuf[eb + mt * 16 + lm];

    // GEMM1: [64x288] @ [288x256]; wave owns 32 output cols
    f32x4 acc[4][2];
#pragma unroll
    for (int mt = 0; mt < 4; mt++)
#pragma unroll
        for (int nt = 0; nt < 2; nt++) acc[mt][nt] = (f32x4){0.f, 0.f, 0.f, 0.f};
#pragma unroll
    for (int kt = 0; kt < 9; kt++) {
        bf16x8 aw[2];
#pragma unroll
        for (int nt = 0; nt < 2; nt++)
            aw[nt] = *(const bf16x8*)(W1s + ((size_t)(kt * 256 + w * 32 + nt * 16 + lm) * 32 + lq * 8));
#pragma unroll
        for (int mt = 0; mt < 4; mt++) {
            bf16x8 bx = *(const bf16x8*)(As + (mt * 16 + lm) * LROW + kt * 32 + lq * 8);
#pragma unroll
            for (int nt = 0; nt < 2; nt++) acc[mt][nt] = MFMA_B16(aw[nt], bx, acc[mt][nt]);
        }
    }
    // y1 = silu(acc + b1) -> Ys packed (disjoint from As)
#pragma unroll
    for (int nt = 0; nt < 2; nt++) {
        int cb = w * 32 + nt * 16 + lq * 4;
        f32x4 bb = *(const f32x4*)(b1 + cb);
#pragma unroll
        for (int mt = 0; mt < 4; mt++) {
            int row = mt * 16 + lm;
            bf16x4 v = {f2bs(silu(acc[mt][nt][0] + bb[0])), f2bs(silu(acc[mt][nt][1] + bb[1])),
                        f2bs(silu(acc[mt][nt][2] + bb[2])), f2bs(silu(acc[mt][nt][3] + bb[3]))};
            *(bf16x4*)(Ys + row * YROW + cb) = v;
        }
    }
    __syncthreads();

    // GEMM2: [64x256] @ [256x256]
#pragma unroll
    for (int mt = 0; mt < 4; mt++)
#pragma unroll
        for (int nt = 0; nt < 2; nt++) acc[mt][nt] = (f32x4){0.f, 0.f, 0.f, 0.f};
#pragma unroll
    for (int kt = 0; kt < 8; kt++) {
        bf16x8 aw[2];
#pragma unroll
        for (int nt = 0; nt < 2; nt++)
            aw[nt] = *(const bf16x8*)(W2s + ((size_t)(kt * 256 + w * 32 + nt * 16 + lm) * 32 + lq * 8));
#pragma unroll
        for (int mt = 0; mt < 4; mt++) {
            bf16x8 bx = *(const bf16x8*)(Ys + (mt * 16 + lm) * YROW + kt * 32 + lq * 8);
#pragma unroll
            for (int nt = 0; nt < 2; nt++) acc[mt][nt] = MFMA_B16(aw[nt], bx, acc[mt][nt]);
        }
    }
    // epilogue: xnew = (x_old + u*silu(acc+b2))/sqrt2; x_old read b64 from As;
    // same thread writes same cells (WAR-safe, no barrier).
    const float rs2 = 0.70710678118654752f;
#pragma unroll
    for (int nt = 0; nt < 2; nt++) {
        int cb = w * 32 + nt * 16 + lq * 4;
        f32x4 bb = *(const f32x4*)(b2 + cb);
#pragma unroll
        for (int mt = 0; mt < 4; mt++) {
            int row = mt * 16 + lm;
            bf16x4 xo = *(const bf16x4*)(As + row * LROW + cb);
            bf16x4 v;
#pragma unroll
            for (int r = 0; r < 4; r++) {
                float xn = (bs2f(xo[r]) + uu[mt] * silu(acc[mt][nt][r] + bb[r])) * rs2;
                v[r] = f2bs(xn);
            }
            *(bf16x4*)(As + row * LROW + cb) = v;
            if (layer == 0) *(bf16x4*)(xb + (size_t)(eb + row) * H + cb) = v;
        }
    }
    __syncthreads();

    if (layer == 0) {
        // wcomp: w = x_new @ Wlwn -- waves 0-3 own edges w*16..w*16+15
        if (w < 4) {
            f32x4 cw = (f32x4){0.f, 0.f, 0.f, 0.f};
#pragma unroll
            for (int kt = 0; kt < 8; kt++) {
                bf16x8 bx = *(const bf16x8*)(As + (w * 16 + lm) * LROW + kt * 32 + lq * 8);
                bf16x8 a = *(const bf16x8*)(Wlwn + ((size_t)(kt * 16 + lm) * 32 + lq * 8));
                cw = MFMA_B16(a, bx, cw);
            }
            *(f32x4*)(wbufn + (size_t)(eb + w * 16 + lm) * 16 + lq * 4) = cw;
        }
    } else {
        // out-proj: edge_out = (x_new @ W_out) * u -> atomicAdd nacc[rcv]
        if (w < 4) {
            f32x4 co = (f32x4){0.f, 0.f, 0.f, 0.f};
#pragma unroll
            for (int kt = 0; kt < 8; kt++) {
                bf16x8 bx = *(const bf16x8*)(As + (w * 16 + lm) * LROW + kt * 32 + lq * 8);
                bf16x8 a = *(const bf16x8*)(Wouts + ((size_t)(kt * 16 + lm) * 32 + lq * 8));
                co = MFMA_B16(a, bx, co);
            }
            if (lq == 0) {
                int e = eb + w * 16 + lm;
                atomicAdd(&nacc[rcv[e]], co[0] * ubuf[e]);
            }
        }
    }
}

__global__ __launch_bounds__(256) void k_final(
    const float* __restrict__ nacc, void* __restrict__ out, const int* __restrict__ flag,
    float inv, int N)
{
    int n = blockIdx.x * 256 + threadIdx.x;
    if (n >= N) return;
    float v = nacc[n] * inv;
    if (*flag) ((float*)out)[n] = v;
    else       ((__hip_bfloat16*)out)[n] = __float2bfloat16(v);
}

extern "C" void kernel_launch(void* const* d_in, const int* in_sizes, int n_in,
                              void* d_out, int out_size, void* d_ws, size_t ws_size,
                              hipStream_t stream)
{
    const int E = in_sizes[2];      // 131072
    const int N = in_sizes[0] / F;  // 8192
    (void)n_in; (void)ws_size; (void)out_size;

    char* wsb = (char*)d_ws;
    size_t off = 0;
    int* flag = (int*)wsb; off += 256;

    const int fidx[14] = {0, 1, 4, 5, 6, 7, 8, 9, 10, 11, 12, 13, 14, 15};
    float* canon[14];
    for (int k = 0; k < 14; k++) {
        canon[k] = (float*)(wsb + off);
        off += (size_t)in_sizes[fidx[k]] * 4;
        off = (off + 255) & ~(size_t)255;
    }
    const float* naC   = canon[0];
    const float* vecC  = canon[1];
    const float* We0C  = canon[2];
    const float* be0C  = canon[3];
    const float* We1C  = canon[4];
    const float* be1C  = canon[5];
    const float* Wv0C  = canon[6];
    const float* WlwC  = canon[7];
    const float* WlshC = canon[8];
    const float* Wly1C = canon[9];
    const float* bly1C = canon[10];
    const float* Wly2C = canon[11];
    const float* bly2C = canon[12];
    const float* WoutC = canon[13];

    // swizzled bf16 weights
    __hip_bfloat16* We0s  = (__hip_bfloat16*)(wsb + off); off += 64 * 256 * 2;
    __hip_bfloat16* We1s  = (__hip_bfloat16*)(wsb + off); off += 256 * 256 * 2;
    __hip_bfloat16* Wv0s  = (__hip_bfloat16*)(wsb + off); off += 256 * 16 * 2;
    __hip_bfloat16* Wlws0 = (__hip_bfloat16*)(wsb + off); off += 256 * 16 * 2;
    __hip_bfloat16* Wlws1 = (__hip_bfloat16*)(wsb + off); off += 256 * 16 * 2;
    __hip_bfloat16* W1s0  = (__hip_bfloat16*)(wsb + off); off += 288 * 256 * 2;
    __hip_bfloat16* W1s1  = (__hip_bfloat16*)(wsb + off); off += 288 * 256 * 2;
    __hip_bfloat16* W2s0  = (__hip_bfloat16*)(wsb + off); off += 256 * 256 * 2;
    __hip_bfloat16* W2s1  = (__hip_bfloat16*)(wsb + off); off += 256 * 256 * 2;
    __hip_bfloat16* Wouts = (__hip_bfloat16*)(wsb + off); off += 256 * 16 * 2;
    off = (off + 255) & ~(size_t)255;

    __hip_bfloat16* xbuf = (__hip_bfloat16*)(wsb + off); off += (size_t)E * H * 2;
    float* wYn0 = (float*)(wsb + off); off += (size_t)N * H * 4;
    __hip_bfloat16* vvbuf = (__hip_bfloat16*)(wsb + off); off += (size_t)E * 16 * 2;
    float* ubuf = (float*)(wsb + off); off += (size_t)E * 4;
    float* Ybuf = (float*)(wsb + off); off += (size_t)E * 16 * 4;
    float* abuf = (float*)(wsb + off); off += (size_t)E * 16 * 4;
    float* wbuf = (float*)(wsb + off); off += (size_t)E * 16 * 4;
    float* nacc = (float*)(wsb + off); off += (size_t)N * 4;
    int* cnt  = (int*)(wsb + off); off += (size_t)N * 4;
    int* offb = (int*)(wsb + off); off += (size_t)(N + 1) * 4;
    int* cur  = (int*)(wsb + off); off += (size_t)N * 4;
    int* eidx = (int*)(wsb + off); off += (size_t)E * 4;

    const int* snd = (const int*)d_in[2];
    const int* rcv = (const int*)d_in[3];
    const float inv = 0.25f;
    const int nb64 = E / 64;

    // dtype sniff + merged canonicalization
    k_sniff<<<1, 256, 0, stream>>>(d_in[1], flag);
    {
        ConvArgs ca;
        int c = 0;
        for (int k = 0; k < 14; k++) {
            ca.src[k] = d_in[fidx[k]];
            ca.dst[k] = canon[k];
            ca.cum[k] = c;
            c += in_sizes[fidx[k]];
        }
        ca.cum[14] = c;
        k_conv_all<<<(c + 255) / 256, 256, 0, stream>>>(ca, flag);
    }

    // merged weight swizzles
    {
        SwzArgs sa;
        const float* srcs[9] = {We0C, We1C, Wv0C, WlwC, WlwC + 256 * 16,
                                Wly1C, Wly1C + 272 * 256, Wly2C, Wly2C + 256 * 256};
        __hip_bfloat16* dsts[9] = {We0s, We1s, Wv0s, Wlws0, Wlws1, W1s0, W1s1, W2s0, W2s1};
        int Ks[9]    = {40, 256, 256, 256, 256, 272, 272, 256, 256};
        int Ncs[9]   = {256, 256, 16, 16, 16, 256, 256, 256, 256};
        int Kpads[9] = {64, 256, 256, 256, 256, 288, 288, 256, 256};
        int c = 0;
        for (int j = 0; j < 9; j++) {
            sa.src[j] = srcs[j]; sa.dst[j] = dsts[j];
            sa.K[j] = Ks[j]; sa.Nc[j] = Ncs[j];
            sa.cum[j] = c;
            c += (Kpads[j] >> 5) * Ncs[j] * 32;
        }
        sa.cum[9] = c;
        k_swz_all<<<(c + 255) / 256, 256, 0, stream>>>(sa);
    }
    k_swz_wout<<<16, 256, 0, stream>>>(WoutC, Wouts);

    // sender CSR
    hipMemsetAsync(cnt, 0, (size_t)N * sizeof(int), stream);
    k_hist<<<(E + 255) / 256, 256, 0, stream>>>(snd, cnt, E);
    k_scan<<<1, 256, 0, stream>>>(cnt, offb, cur, N);
    k_cscatter<<<(E + 255) / 256, 256, 0, stream>>>(snd, cur, eidx, E);

    // embed (fused geometry)
    k_embed_mfma<<<nb64, 512, 0, stream>>>(vecC, naC, snd, rcv,
                                           We0s, be0C, We1s, be1C, Wv0s, Wlws0,
                                           ubuf, Ybuf, xbuf, abuf, wbuf);

    // layer 0: gather0 emits wYn0 + vv0; layer kernel emits w for layer 1
    k_gather0<<<N / 4, 256, 0, stream>>>(offb, eidx, wbuf, Ybuf, abuf, wYn0, vvbuf);
    k_layer_mfma<<<nb64, 512, 0, stream>>>(xbuf, ubuf, vvbuf, rcv,
                                           W1s0, bly1C, W2s0, bly2C,
                                           Wlws1, wbuf,
                                           (const __hip_bfloat16*)nullptr, (float*)nullptr, 0);
    // layer 1: gather1 emits vv1 (wYn1 kept local); fused out-proj -> nacc
    hipMemsetAsync(nacc, 0, (size_t)N * sizeof(float), stream);
    k_gather1<<<N / 4, 256, 0, stream>>>(offb, eidx, wbuf, Ybuf, abuf, wYn0, WlshC, vvbuf);
    k_layer_mfma<<<nb64, 512, 0, stream>>>(xbuf, ubuf, vvbuf, rcv,
                                           W1s1, bly1C + H, W2s1, bly2C + H,
                                           (const __hip_bfloat16*)nullptr, (float*)nullptr,
                                           Wouts, nacc, 1);

    k_final<<<(N + 255) / 256, 256, 0, stream>>>(nacc, d_out, flag, inv, N);
}

// Round 12
// 348.098 us; speedup vs baseline: 1.3553x; 1.0355x over previous
//
#include <hip/hip_runtime.h>
#include <hip/hip_bf16.h>
#include <math.h>

#define H 256
#define F 16
#define MUL 16
#define NB 8
#define LROW 296   // As row stride (elems): 148 dwords == 20 mod 32 -> 2-way (free)
#define YROW 264   // Ys row stride (elems): 132 dwords == 4 mod 32  -> 2-way (free)

typedef short bf16x8 __attribute__((ext_vector_type(8)));
typedef short bf16x4 __attribute__((ext_vector_type(4)));
typedef float f32x4 __attribute__((ext_vector_type(4)));
#define MFMA_B16(a, b, c) __builtin_amdgcn_mfma_f32_16x16x32_bf16(a, b, c, 0, 0, 0)

__device__ __forceinline__ float bf2f(__hip_bfloat16 x) { return __bfloat162float(x); }
// silu via v_rcp (no -ffast-math: plain '/' emits the full div-fixup chain)
__device__ __forceinline__ float silu(float x)
{
    return x * __builtin_amdgcn_rcpf(1.f + __expf(-x));
}
__device__ __forceinline__ short f2bs(float x)
{
    __hip_bfloat16 h = __float2bfloat16(x);
    short s; __builtin_memcpy(&s, &h, 2); return s;
}
__device__ __forceinline__ float bs2f(short s)
{
    __hip_bfloat16 h; __builtin_memcpy(&h, &s, 2); return __bfloat162float(h);
}

// ---------------- dtype sniffer: bf16 (flag=0) or fp32 (flag=1)?
__global__ __launch_bounds__(256) void k_sniff(const void* vec, int* flag)
{
    __shared__ int bad;
    int tid = threadIdx.x;
    if (tid == 0) bad = 0;
    __syncthreads();
    const __hip_bfloat16* hp = (const __hip_bfloat16*)vec;
    for (int i = tid; i < 1024; i += 256) {
        float f = bf2f(hp[i]);
        if (!(isfinite(f) && fabsf(f) <= 1.0f)) bad = 1;
    }
    __syncthreads();
    if (tid == 0) *flag = bad;
}

// ---------------- merged converter: 14 float inputs -> canonical fp32
struct ConvArgs {
    const void* src[14];
    float* dst[14];
    int cum[15];
};
__global__ __launch_bounds__(256) void k_conv_all(ConvArgs a, const int* __restrict__ flag)
{
    int gid = blockIdx.x * 256 + threadIdx.x;
    if (gid >= a.cum[14]) return;
    int k = 0;
    while (gid >= a.cum[k + 1]) k++;
    int i = gid - a.cum[k];
    float v = (*flag) ? ((const float*)a.src[k])[i]
                      : bf2f(((const __hip_bfloat16*)a.src[k])[i]);
    a.dst[k][i] = v;
}

// ---------------- merged weight swizzle: fp32 [K][N] -> bf16 frag-linear
struct SwzArgs {
    const float* src[9];
    __hip_bfloat16* dst[9];
    int K[9], Nc[9], cum[10];
};
__global__ __launch_bounds__(256) void k_swz_all(SwzArgs a)
{
    int gid = blockIdx.x * 256 + threadIdx.x;
    if (gid >= a.cum[9]) return;
    int j = 0;
    while (gid >= a.cum[j + 1]) j++;
    int idx = gid - a.cum[j];
    int kk = idx & 31;
    int n = (idx >> 5) % a.Nc[j];
    int kt = idx / (32 * a.Nc[j]);
    int k = kt * 32 + kk;
    float v = (k < a.K[j]) ? a.src[j][(size_t)k * a.Nc[j] + n] : 0.f;
    a.dst[j][idx] = __float2bfloat16(v);
}

// ---------------- W_out swizzle: [256][1] -> frag-linear [256x16], col 0 only
__global__ __launch_bounds__(256) void k_swz_wout(const float* __restrict__ Wout,
                                                  __hip_bfloat16* __restrict__ dst)
{
    int idx = blockIdx.x * 256 + threadIdx.x;   // 4096 total
    if (idx >= 8 * 16 * 32) return;
    int kk = idx & 31;
    int n = (idx >> 5) & 15;
    int kt = idx >> 9;
    float v = (n == 0) ? Wout[kt * 32 + kk] : 0.f;
    dst[idx] = __float2bfloat16(v);
}

// ---------------- CSR build
__global__ __launch_bounds__(256) void k_hist(const int* __restrict__ snd,
                                              int* __restrict__ cnt, int E)
{
    int e = blockIdx.x * 256 + threadIdx.x;
    if (e < E) atomicAdd(&cnt[snd[e]], 1);
}

__global__ __launch_bounds__(256) void k_scan(const int* __restrict__ cnt,
                                              int* __restrict__ off,
                                              int* __restrict__ cur, int N)
{
    __shared__ int sums[256];
    int tid = threadIdx.x;
    int chunk = (N + 255) / 256;
    int base = tid * chunk;
    int s = 0;
    for (int i = 0; i < chunk; i++) { int idx = base + i; if (idx < N) s += cnt[idx]; }
    sums[tid] = s;
    __syncthreads();
    for (int d = 1; d < 256; d <<= 1) {
        int v = (tid >= d) ? sums[tid - d] : 0;
        __syncthreads();
        sums[tid] += v;
        __syncthreads();
    }
    int run = (tid == 0) ? 0 : sums[tid - 1];
    for (int i = 0; i < chunk; i++) {
        int idx = base + i;
        if (idx < N) { off[idx] = run; cur[idx] = run; run += cnt[idx]; }
    }
    if (tid == 255) off[N] = run;
}

__global__ __launch_bounds__(256) void k_cscatter(const int* __restrict__ snd,
                                                  int* __restrict__ cur,
                                                  int* __restrict__ eidx, int E)
{
    int e = blockIdx.x * 256 + threadIdx.x;
    if (e >= E) return;
    int p = atomicAdd(&cur[snd[e]], 1);
    eidx[p] = e;
}

// =====================================================================
// Tile kernels (operand-swapped): A-operand = weight frag, B-operand = x frag
// Block = 64 edges x 8 waves (512 thr); wave w owns outcol slice 32w..32w+31.
// Dual LDS buffers (71680 B) -> 2 blocks/CU, 16 waves/CU (measured optimum;
// blocks/CU>2 L2-write-amplifies, thin waves regress). vv precomputed (r5).
// This round: manual 2-kt weight-frag PREFETCH across each barrier --
// compiler can't hoist global loads above __syncthreads, so post-barrier
// all waves stall on the first weight load in lockstep; preloading kt=0,1
// into registers hides the L2 latency under the barrier+LDS work.
// =====================================================================

// ---------------- MFMA embed tile kernel with fused geometry prologue
__global__ __launch_bounds__(512, 4) void k_embed_mfma(
    const float* __restrict__ vec, const float* __restrict__ na,
    const int* __restrict__ snd, const int* __restrict__ rcv,
    const __hip_bfloat16* __restrict__ We0s, const float* __restrict__ be0,
    const __hip_bfloat16* __restrict__ We1s, const float* __restrict__ be1,
    const __hip_bfloat16* __restrict__ Wv0s, const __hip_bfloat16* __restrict__ Wlws0,
    float* __restrict__ ubuf, float* __restrict__ Ybuf,
    __hip_bfloat16* __restrict__ xb, float* __restrict__ abuf,
    float* __restrict__ wbuf)
{
    __shared__ __align__(16) __hip_bfloat16 As[64 * LROW];  // 37888 B
    __shared__ __align__(16) __hip_bfloat16 Ys[64 * YROW];  // 33792 B
    __shared__ float us[64];
    int tid = threadIdx.x;
    int w = tid >> 6, l = tid & 63;
    int lm = l & 15, lq = l >> 4;
    int eb = blockIdx.x * 64;

    // prefetch GEMM1 weights (both kts) BEFORE the staging barrier
    bf16x8 w0p[2][2];
#pragma unroll
    for (int kt = 0; kt < 2; kt++)
#pragma unroll
        for (int nt = 0; nt < 2; nt++)
            w0p[kt][nt] = *(const bf16x8*)(We0s + ((size_t)(kt * 256 + w * 32 + nt * 16 + lm) * 32 + lq * 8));

    // ---- fused geometry: features straight into As; u,Y to global ----
    {
        int el = tid & 63;
        int part = tid >> 6;
        int ge = eb + el;
        const float SQ2 = 1.41421356237309515f;
        const float PI = 3.14159265358979323846f;
        if (part == 0) {
            float vx = vec[3 * ge + 0], vy = vec[3 * ge + 1], vz = vec[3 * ge + 2];
            float d = sqrtf(vx * vx + vy * vy + vz * vz);
            float d3 = d * d * d;
            float d6 = d3 * d3, d7 = d6 * d, d8 = d7 * d;
            float u = 1.f - 28.f * d6 + 48.f * d7 - 21.f * d8;
            u = (d < 1.f) ? u : 0.f;
            ubuf[ge] = u;
            us[el] = u;
            float invd = __builtin_amdgcn_rcpf(d);
#pragma unroll
            for (int k = 1; k <= 4; k++)
                As[el * LROW + (k - 1)] = __float2bfloat16(SQ2 * __sinf((float)k * PI * d) * invd);
        } else if (part == 4) {
            float vx = vec[3 * ge + 0], vy = vec[3 * ge + 1], vz = vec[3 * ge + 2];
            float d = sqrtf(vx * vx + vy * vy + vz * vz);
            float invd = __builtin_amdgcn_rcpf(d);
#pragma unroll
            for (int k = 5; k <= 8; k++)
                As[el * LROW + (k - 1)] = __float2bfloat16(SQ2 * __sinf((float)k * PI * d) * invd);
        } else if (part == 5) {
#pragma unroll
            for (int j = 40; j < 64; j++) As[el * LROW + j] = __float2bfloat16(0.f);
        } else if (part == 1) {
            int s = snd[ge];
#pragma unroll
            for (int j = 0; j < 16; j++)
                As[el * LROW + 8 + j] = __float2bfloat16(na[(size_t)s * F + j]);
        } else if (part == 2) {
            int r = rcv[ge];
#pragma unroll
            for (int j = 0; j < 16; j++)
                As[el * LROW + 24 + j] = __float2bfloat16(na[(size_t)r * F + j]);
        } else if (part == 3) {
            float vx = vec[3 * ge + 0], vy = vec[3 * ge + 1], vz = vec[3 * ge + 2];
            float d = sqrtf(vx * vx + vy * vy + vz * vz);
            float invd = __builtin_amdgcn_rcpf(d);
            float x = vx * invd, y = vy * invd, z = vz * invd;
            const float s3 = 1.7320508075688772f;
            const float s5 = 2.2360679774997896f;
            const float s15 = 3.8729833462074170f;
            const float s7 = 2.6457513110645907f;
            const float c33 = 2.0916500663351889f;
            const float c32 = 10.246950765959598f;
            const float c31 = 1.6201851746019651f;
            float* Yp = Ybuf + (size_t)ge * 16;
            Yp[0] = 1.f;
            Yp[1] = s3 * x;  Yp[2] = s3 * y;  Yp[3] = s3 * z;
            Yp[4] = s15 * x * y;  Yp[5] = s15 * y * z;
            Yp[6] = 0.5f * s5 * (3.f * z * z - 1.f);
            Yp[7] = s15 * x * z;
            Yp[8] = 0.5f * s15 * (x * x - y * y);
            Yp[9] = c33 * y * (3.f * x * x - y * y);
            Yp[10] = c32 * x * y * z;
            Yp[11] = c31 * y * (5.f * z * z - 1.f);
            Yp[12] = 0.5f * s7 * (5.f * z * z * z - 3.f * z);
            Yp[13] = c31 * x * (5.f * z * z - 1.f);
            Yp[14] = 0.5f * c32 * z * (x * x - y * y);
            Yp[15] = c33 * x * (x * x - 3.f * y * y);
        }
    }
    __syncthreads();

    // GEMM1: [64x64] @ [64x256]  (weights preloaded); wave owns 32 cols
    f32x4 acc[4][2];
#pragma unroll
    for (int mt = 0; mt < 4; mt++)
#pragma unroll
        for (int nt = 0; nt < 2; nt++) acc[mt][nt] = (f32x4){0.f, 0.f, 0.f, 0.f};
#pragma unroll
    for (int kt = 0; kt < 2; kt++) {
#pragma unroll
        for (int mt = 0; mt < 4; mt++) {
            bf16x8 bx = *(const bf16x8*)(As + (mt * 16 + lm) * LROW + kt * 32 + lq * 8);
#pragma unroll
            for (int nt = 0; nt < 2; nt++) acc[mt][nt] = MFMA_B16(w0p[kt][nt], bx, acc[mt][nt]);
        }
    }
    // prefetch GEMM2 kt=0,1 before the Ys barrier
    bf16x8 w1p[2][2];
#pragma unroll
    for (int kt = 0; kt < 2; kt++)
#pragma unroll
        for (int nt = 0; nt < 2; nt++)
            w1p[kt][nt] = *(const bf16x8*)(We1s + ((size_t)(kt * 256 + w * 32 + nt * 16 + lm) * 32 + lq * 8));
    // y0 = silu(acc + b0) -> Ys (disjoint from As: no barrier before writes)
#pragma unroll
    for (int nt = 0; nt < 2; nt++) {
        int cb = w * 32 + nt * 16 + lq * 4;
        f32x4 bb = *(const f32x4*)(be0 + cb);
#pragma unroll
        for (int mt = 0; mt < 4; mt++) {
            int row = mt * 16 + lm;
            bf16x4 v = {f2bs(silu(acc[mt][nt][0] + bb[0])), f2bs(silu(acc[mt][nt][1] + bb[1])),
                        f2bs(silu(acc[mt][nt][2] + bb[2])), f2bs(silu(acc[mt][nt][3] + bb[3]))};
            *(bf16x4*)(Ys + row * YROW + cb) = v;
        }
    }
    __syncthreads();

    // GEMM2: [64x256] @ [256x256]
#pragma unroll
    for (int mt = 0; mt < 4; mt++)
#pragma unroll
        for (int nt = 0; nt < 2; nt++) acc[mt][nt] = (f32x4){0.f, 0.f, 0.f, 0.f};
#pragma unroll
    for (int kt = 0; kt < 8; kt++) {
        bf16x8 aw[2];
#pragma unroll
        for (int nt = 0; nt < 2; nt++)
            aw[nt] = (kt < 2) ? w1p[kt][nt]
                   : *(const bf16x8*)(We1s + ((size_t)(kt * 256 + w * 32 + nt * 16 + lm) * 32 + lq * 8));
#pragma unroll
        for (int mt = 0; mt < 4; mt++) {
            bf16x8 bx = *(const bf16x8*)(Ys + (mt * 16 + lm) * YROW + kt * 32 + lq * 8);
#pragma unroll
            for (int nt = 0; nt < 2; nt++) acc[mt][nt] = MFMA_B16(aw[nt], bx, acc[mt][nt]);
        }
    }
    // prefetch GEMM3 tail weights (2 kts) before epilogue barrier
    const __hip_bfloat16* tw = (w < 4) ? Wv0s : Wlws0;
    bf16x8 twp[2];
#pragma unroll
    for (int kt = 0; kt < 2; kt++)
        twp[kt] = *(const bf16x8*)(tw + ((size_t)(kt * 16 + lm) * 32 + lq * 8));
    // epilogue: x1 = silu(.)*u -> xb global (8B stores) and As
#pragma unroll
    for (int nt = 0; nt < 2; nt++) {
        int cb = w * 32 + nt * 16 + lq * 4;
        f32x4 bb = *(const f32x4*)(be1 + cb);
#pragma unroll
        for (int mt = 0; mt < 4; mt++) {
            int row = mt * 16 + lm;
            float uu = us[row];
            bf16x4 v = {f2bs(silu(acc[mt][nt][0] + bb[0]) * uu),
                        f2bs(silu(acc[mt][nt][1] + bb[1]) * uu),
                        f2bs(silu(acc[mt][nt][2] + bb[2]) * uu),
                        f2bs(silu(acc[mt][nt][3] + bb[3]) * uu)};
            *(bf16x4*)(As + row * LROW + cb) = v;
            *(bf16x4*)(xb + (size_t)(eb + row) * H + cb) = v;
        }
    }
    __syncthreads();

    // GEMM3: a = x@Wv0 (waves 0-3), w = x@Wlw0 (waves 4-7)
    if (w < 4) {
        f32x4 av = (f32x4){0.f, 0.f, 0.f, 0.f};
#pragma unroll
        for (int kt = 0; kt < 8; kt++) {
            bf16x8 bx = *(const bf16x8*)(As + (w * 16 + lm) * LROW + kt * 32 + lq * 8);
            bf16x8 a_v = (kt < 2) ? twp[kt]
                       : *(const bf16x8*)(Wv0s + ((size_t)(kt * 16 + lm) * 32 + lq * 8));
            av = MFMA_B16(a_v, bx, av);
        }
        *(f32x4*)(abuf + (size_t)(eb + w * 16 + lm) * 16 + lq * 4) = av;
    } else {
        int w2 = w - 4;
        f32x4 aw2 = (f32x4){0.f, 0.f, 0.f, 0.f};
#pragma unroll
        for (int kt = 0; kt < 8; kt++) {
            bf16x8 bx = *(const bf16x8*)(As + (w2 * 16 + lm) * LROW + kt * 32 + lq * 8);
            bf16x8 a_w = (kt < 2) ? twp[kt]
                       : *(const bf16x8*)(Wlws0 + ((size_t)(kt * 16 + lm) * 32 + lq * 8));
            aw2 = MFMA_B16(a_w, bx, aw2);
        }
        *(f32x4*)(wbuf + (size_t)(eb + w2 * 16 + lm) * 16 + lq * 4) = aw2;
    }
}

// ---------------- gather #1: wYn0 = inv*segsum(w ⊗ Y)  AND  vv0[e,m] =
// wYn0[s,m,0]*a[e,m].  Pass 2 de-staged: vv0 needs no cross-thread data,
// so thread (m->edge slot, i->col) loads abuf directly -- no LDS staging,
// no barriers in pass 2.
__global__ __launch_bounds__(256) void k_gather0(
    const int* __restrict__ off, const int* __restrict__ eidx,
    const float* __restrict__ wbuf, const float* __restrict__ Ybuf,
    const float* __restrict__ abuf,
    float* __restrict__ wYn0, __hip_bfloat16* __restrict__ vvbuf)
{
    __shared__ float ws[16][17];
    __shared__ float Ysh[16][17];
    __shared__ float w00[16];
    int tid = threadIdx.x;
    int m = tid >> 4, i = tid & 15;
    for (int nn = 0; nn < 4; nn++) {
        int n = blockIdx.x * 4 + nn;
        int beg = off[n], end = off[n + 1];
        float acc = 0.f;
        for (int c = beg; c < end; c += 16) {
            int ne = min(16, end - c);
            if (m < ne) {
                int e = eidx[c + m];
                ws[m][i] = wbuf[(size_t)e * 16 + i];
                Ysh[m][i] = Ybuf[(size_t)e * 16 + i];
            }
            __syncthreads();
            for (int j2 = 0; j2 < ne; j2++) acc += ws[j2][m] * Ysh[j2][i];
            __syncthreads();
        }
        wYn0[(size_t)n * 256 + m * 16 + i] = acc * 0.25f;
        if (i == 0) w00[m] = acc * 0.25f;
        __syncthreads();
        // pass 2 (no staging, no barriers): vv0[e,i] = w00[i]*a[e,i]
        float w0i = w00[i];
        for (int c = beg + m; c < end; c += 16) {
            int e = eidx[c];
            float a = abuf[(size_t)e * 16 + i];
            vvbuf[(size_t)e * 16 + i] = __float2bfloat16(w0i * a);
        }
        __syncthreads();   // protect ws/Ysh/w00 reuse for next node
    }
}

// ---------------- gather #2: wYn1 (local only) AND vv1[e,m] =
// wYn1[s,m,0]*a[e,m]*sum_i wYn0[s,m,i]*Wlsh0[i,0]*Y[e,i].  Pass 2
// de-staged: per-thread direct f32x4 reads of Y[e] + qsh from LDS.
__global__ __launch_bounds__(256) void k_gather1(
    const int* __restrict__ off, const int* __restrict__ eidx,
    const float* __restrict__ wbuf, const float* __restrict__ Ybuf,
    const float* __restrict__ abuf,
    const float* __restrict__ wYn0, const float* __restrict__ Wlsh,
    __hip_bfloat16* __restrict__ vvbuf)
{
    __shared__ float ws[16][17];
    __shared__ float Ysh[16][17];
    __shared__ float qsh[16][17];
    __shared__ float w10[16];
    int tid = threadIdx.x;
    int m = tid >> 4, i = tid & 15;
    for (int nn = 0; nn < 4; nn++) {
        int n = blockIdx.x * 4 + nn;
        int beg = off[n], end = off[n + 1];
        float acc = 0.f;
        for (int c = beg; c < end; c += 16) {
            int ne = min(16, end - c);
            if (m < ne) {
                int e = eidx[c + m];
                ws[m][i] = wbuf[(size_t)e * 16 + i];
                Ysh[m][i] = Ybuf[(size_t)e * 16 + i];
            }
            __syncthreads();
            for (int j2 = 0; j2 < ne; j2++) acc += ws[j2][m] * Ysh[j2][i];
            __syncthreads();
        }
        if (i == 0) w10[m] = acc * 0.25f;
        qsh[m][i] = wYn0[(size_t)n * 256 + m * 16 + i] * Wlsh[i * 16];
        __syncthreads();
        // pass 2 (no staging, no barriers)
        float w1i = w10[i];
        for (int c = beg + m; c < end; c += 16) {
            int e = eidx[c];
            float a = abuf[(size_t)e * 16 + i];
            float t = 0.f;
#pragma unroll
            for (int j = 0; j < 4; j++) {
                f32x4 yv = *(const f32x4*)(Ybuf + (size_t)e * 16 + 4 * j);
                t += qsh[i][4 * j + 0] * yv[0] + qsh[i][4 * j + 1] * yv[1]
                   + qsh[i][4 * j + 2] * yv[2] + qsh[i][4 * j + 3] * yv[3];
            }
            vvbuf[(size_t)e * 16 + i] = __float2bfloat16(w1i * a * t);
        }
        __syncthreads();   // protect ws/Ysh/qsh/w10 reuse for next node
    }
}

// ---------------- MFMA layer tile kernel (operand-swapped, dual buffer,
//                  vv precomputed, 2-kt weight prefetch across barriers)
__global__ __launch_bounds__(512, 4) void k_layer_mfma(
    __hip_bfloat16* __restrict__ xb, const float* __restrict__ ubuf,
    const __hip_bfloat16* __restrict__ vvbuf, const int* __restrict__ rcv,
    const __hip_bfloat16* __restrict__ W1s, const float* __restrict__ b1,
    const __hip_bfloat16* __restrict__ W2s, const float* __restrict__ b2,
    const __hip_bfloat16* __restrict__ Wlwn, float* __restrict__ wbufn,
    const __hip_bfloat16* __restrict__ Wouts, float* __restrict__ nacc,
    int layer)
{
    __shared__ __align__(16) __hip_bfloat16 As[64 * LROW];  // x | vv | 0
    __shared__ __align__(16) __hip_bfloat16 Ys[64 * YROW];  // hidden
    int tid = threadIdx.x;
    int w = tid >> 6, l = tid & 63;
    int lm = l & 15, lq = l >> 4;
    int eb = blockIdx.x * 64;

    // prefetch GEMM1 kt=0,1 BEFORE staging barrier
    bf16x8 w1p[2][2];
#pragma unroll
    for (int kt = 0; kt < 2; kt++)
#pragma unroll
        for (int nt = 0; nt < 2; nt++)
            w1p[kt][nt] = *(const bf16x8*)(W1s + ((size_t)(kt * 256 + w * 32 + nt * 16 + lm) * 32 + lq * 8));

    // stage x tile [64x256] -> As cols 0..256 (512 threads: 4 iters)
#pragma unroll
    for (int i = 0; i < 4; i++) {
        int c = tid + 512 * i;
        int row = c >> 5, kc = c & 31;
        *(bf16x8*)(As + row * LROW + kc * 8) =
            *(const bf16x8*)(xb + (size_t)(eb + row) * H + kc * 8);
    }
    // vv: coalesced 4B/thread from vvbuf; zeros 272..288
    {
        int el = tid & 63;
        int mh = (tid >> 6) * 2;     // 8 groups x 2 m each
        int ge = eb + el;
        *(unsigned int*)(As + el * LROW + 256 + mh) =
            *(const unsigned int*)((const short*)vvbuf + (size_t)ge * 16 + mh);
        if (tid < 64) {
#pragma unroll
            for (int j = 0; j < 16; j++) As[tid * LROW + 272 + j] = __float2bfloat16(0.f);
        }
    }
    __syncthreads();

    float uu[4];
#pragma unroll
    for (int mt = 0; mt < 4; mt++) uu[mt] = ubuf[eb + mt * 16 + lm];

    // GEMM1: [64x288] @ [288x256]; wave owns 32 output cols
    f32x4 acc[4][2];
#pragma unroll
    for (int mt = 0; mt < 4; mt++)
#pragma unroll
        for (int nt = 0; nt < 2; nt++) acc[mt][nt] = (f32x4){0.f, 0.f, 0.f, 0.f};
#pragma unroll
    for (int kt = 0; kt < 9; kt++) {
        bf16x8 aw[2];
#pragma unroll
        for (int nt = 0; nt < 2; nt++)
            aw[nt] = (kt < 2) ? w1p[kt][nt]
                   : *(const bf16x8*)(W1s + ((size_t)(kt * 256 + w * 32 + nt * 16 + lm) * 32 + lq * 8));
#pragma unroll
        for (int mt = 0; mt < 4; mt++) {
            bf16x8 bx = *(const bf16x8*)(As + (mt * 16 + lm) * LROW + kt * 32 + lq * 8);
#pragma unroll
            for (int nt = 0; nt < 2; nt++) acc[mt][nt] = MFMA_B16(aw[nt], bx, acc[mt][nt]);
        }
    }
    // prefetch GEMM2 kt=0,1 before the Ys barrier
    bf16x8 w2p[2][2];
#pragma unroll
    for (int kt = 0; kt < 2; kt++)
#pragma unroll
        for (int nt = 0; nt < 2; nt++)
            w2p[kt][nt] = *(const bf16x8*)(W2s + ((size_t)(kt * 256 + w * 32 + nt * 16 + lm) * 32 + lq * 8));
    // y1 = silu(acc + b1) -> Ys packed (disjoint from As)
#pragma unroll
    for (int nt = 0; nt < 2; nt++) {
        int cb = w * 32 + nt * 16 + lq * 4;
        f32x4 bb = *(const f32x4*)(b1 + cb);
#pragma unroll
        for (int mt = 0; mt < 4; mt++) {
            int row = mt * 16 + lm;
            bf16x4 v = {f2bs(silu(acc[mt][nt][0] + bb[0])), f2bs(silu(acc[mt][nt][1] + bb[1])),
                        f2bs(silu(acc[mt][nt][2] + bb[2])), f2bs(silu(acc[mt][nt][3] + bb[3]))};
            *(bf16x4*)(Ys + row * YROW + cb) = v;
        }
    }
    __syncthreads();

    // GEMM2: [64x256] @ [256x256]
#pragma unroll
    for (int mt = 0; mt < 4; mt++)
#pragma unroll
        for (int nt = 0; nt < 2; nt++) acc[mt][nt] = (f32x4){0.f, 0.f, 0.f, 0.f};
#pragma unroll
    for (int kt = 0; kt < 8; kt++) {
        bf16x8 aw[2];
#pragma unroll
        for (int nt = 0; nt < 2; nt++)
            aw[nt] = (kt < 2) ? w2p[kt][nt]
                   : *(const bf16x8*)(W2s + ((size_t)(kt * 256 + w * 32 + nt * 16 + lm) * 32 + lq * 8));
#pragma unroll
        for (int mt = 0; mt < 4; mt++) {
            bf16x8 bx = *(const bf16x8*)(Ys + (mt * 16 + lm) * YROW + kt * 32 + lq * 8);
#pragma unroll
            for (int nt = 0; nt < 2; nt++) acc[mt][nt] = MFMA_B16(aw[nt], bx, acc[mt][nt]);
        }
    }
    // prefetch tail weights (2 kts) before epilogue barrier (waves 0-3 only use them)
    const __hip_bfloat16* tw = (layer == 0) ? Wlwn : Wouts;
    bf16x8 twp[2];
#pragma unroll
    for (int kt = 0; kt < 2; kt++)
        twp[kt] = *(const bf16x8*)(tw + ((size_t)(kt * 16 + lm) * 32 + lq * 8));
    // epilogue: xnew = (x_old + u*silu(acc+b2))/sqrt2; x_old read b64 from As;
    // same thread writes same cells (WAR-safe, no barrier).
    const float rs2 = 0.70710678118654752f;
#pragma unroll
    for (int nt = 0; nt < 2; nt++) {
        int cb = w * 32 + nt * 16 + lq * 4;
        f32x4 bb = *(const f32x4*)(b2 + cb);
#pragma unroll
        for (int mt = 0; mt < 4; mt++) {
            int row = mt * 16 + lm;
            bf16x4 xo = *(const bf16x4*)(As + row * LROW + cb);
            bf16x4 v;
#pragma unroll
            for (int r = 0; r < 4; r++) {
                float xn = (bs2f(xo[r]) + uu[mt] * silu(acc[mt][nt][r] + bb[r])) * rs2;
                v[r] = f2bs(xn);
            }
            *(bf16x4*)(As + row * LROW + cb) = v;
            if (layer == 0) *(bf16x4*)(xb + (size_t)(eb + row) * H + cb) = v;
        }
    }
    __syncthreads();

    if (layer == 0) {
        // wcomp: w = x_new @ Wlwn -- waves 0-3 own edges w*16..w*16+15
        if (w < 4) {
            f32x4 cw = (f32x4){0.f, 0.f, 0.f, 0.f};
#pragma unroll
            for (int kt = 0; kt < 8; kt++) {
                bf16x8 bx = *(const bf16x8*)(As + (w * 16 + lm) * LROW + kt * 32 + lq * 8);
                bf16x8 a = (kt < 2) ? twp[kt]
                         : *(const bf16x8*)(Wlwn + ((size_t)(kt * 16 + lm) * 32 + lq * 8));
                cw = MFMA_B16(a, bx, cw);
            }
            *(f32x4*)(wbufn + (size_t)(eb + w * 16 + lm) * 16 + lq * 4) = cw;
        }
    } else {
        // out-proj: edge_out = (x_new @ W_out) * u -> atomicAdd nacc[rcv]
        if (w < 4) {
            f32x4 co = (f32x4){0.f, 0.f, 0.f, 0.f};
#pragma unroll
            for (int kt = 0; kt < 8; kt++) {
                bf16x8 bx = *(const bf16x8*)(As + (w * 16 + lm) * LROW + kt * 32 + lq * 8);
                bf16x8 a = (kt < 2) ? twp[kt]
                         : *(const bf16x8*)(Wouts + ((size_t)(kt * 16 + lm) * 32 + lq * 8));
                co = MFMA_B16(a, bx, co);
            }
            if (lq == 0) {
                int e = eb + w * 16 + lm;
                atomicAdd(&nacc[rcv[e]], co[0] * ubuf[e]);
            }
        }
    }
}

__global__ __launch_bounds__(256) void k_final(
    const float* __restrict__ nacc, void* __restrict__ out, const int* __restrict__ flag,
    float inv, int N)
{
    int n = blockIdx.x * 256 + threadIdx.x;
    if (n >= N) return;
    float v = nacc[n] * inv;
    if (*flag) ((float*)out)[n] = v;
    else       ((__hip_bfloat16*)out)[n] = __float2bfloat16(v);
}

extern "C" void kernel_launch(void* const* d_in, const int* in_sizes, int n_in,
                              void* d_out, int out_size, void* d_ws, size_t ws_size,
                              hipStream_t stream)
{
    const int E = in_sizes[2];      // 131072
    const int N = in_sizes[0] / F;  // 8192
    (void)n_in; (void)ws_size; (void)out_size;

    char* wsb = (char*)d_ws;
    size_t off = 0;
    int* flag = (int*)wsb; off += 256;

    const int fidx[14] = {0, 1, 4, 5, 6, 7, 8, 9, 10, 11, 12, 13, 14, 15};
    float* canon[14];
    for (int k = 0; k < 14; k++) {
        canon[k] = (float*)(wsb + off);
        off += (size_t)in_sizes[fidx[k]] * 4;
        off = (off + 255) & ~(size_t)255;
    }
    const float* naC   = canon[0];
    const float* vecC  = canon[1];
    const float* We0C  = canon[2];
    const float* be0C  = canon[3];
    const float* We1C  = canon[4];
    const float* be1C  = canon[5];
    const float* Wv0C  = canon[6];
    const float* WlwC  = canon[7];
    const float* WlshC = canon[8];
    const float* Wly1C = canon[9];
    const float* bly1C = canon[10];
    const float* Wly2C = canon[11];
    const float* bly2C = canon[12];
    const float* WoutC = canon[13];

    // swizzled bf16 weights
    __hip_bfloat16* We0s  = (__hip_bfloat16*)(wsb + off); off += 64 * 256 * 2;
    __hip_bfloat16* We1s  = (__hip_bfloat16*)(wsb + off); off += 256 * 256 * 2;
    __hip_bfloat16* Wv0s  = (__hip_bfloat16*)(wsb + off); off += 256 * 16 * 2;
    __hip_bfloat16* Wlws0 = (__hip_bfloat16*)(wsb + off); off += 256 * 16 * 2;
    __hip_bfloat16* Wlws1 = (__hip_bfloat16*)(wsb + off); off += 256 * 16 * 2;
    __hip_bfloat16* W1s0  = (__hip_bfloat16*)(wsb + off); off += 288 * 256 * 2;
    __hip_bfloat16* W1s1  = (__hip_bfloat16*)(wsb + off); off += 288 * 256 * 2;
    __hip_bfloat16* W2s0  = (__hip_bfloat16*)(wsb + off); off += 256 * 256 * 2;
    __hip_bfloat16* W2s1  = (__hip_bfloat16*)(wsb + off); off += 256 * 256 * 2;
    __hip_bfloat16* Wouts = (__hip_bfloat16*)(wsb + off); off += 256 * 16 * 2;
    off = (off + 255) & ~(size_t)255;

    __hip_bfloat16* xbuf = (__hip_bfloat16*)(wsb + off); off += (size_t)E * H * 2;
    float* wYn0 = (float*)(wsb + off); off += (size_t)N * H * 4;
    __hip_bfloat16* vvbuf = (__hip_bfloat16*)(wsb + off); off += (size_t)E * 16 * 2;
    float* ubuf = (float*)(wsb + off); off += (size_t)E * 4;
    float* Ybuf = (float*)(wsb + off); off += (size_t)E * 16 * 4;
    float* abuf = (float*)(wsb + off); off += (size_t)E * 16 * 4;
    float* wbuf = (float*)(wsb + off); off += (size_t)E * 16 * 4;
    float* nacc = (float*)(wsb + off); off += (size_t)N * 4;
    int* cnt  = (int*)(wsb + off); off += (size_t)N * 4;
    int* offb = (int*)(wsb + off); off += (size_t)(N + 1) * 4;
    int* cur  = (int*)(wsb + off); off += (size_t)N * 4;
    int* eidx = (int*)(wsb + off); off += (size_t)E * 4;

    const int* snd = (const int*)d_in[2];
    const int* rcv = (const int*)d_in[3];
    const float inv = 0.25f;
    const int nb64 = E / 64;

    // dtype sniff + merged canonicalization
    k_sniff<<<1, 256, 0, stream>>>(d_in[1], flag);
    {
        ConvArgs ca;
        int c = 0;
        for (int k = 0; k < 14; k++) {
            ca.src[k] = d_in[fidx[k]];
            ca.dst[k] = canon[k];
            ca.cum[k] = c;
            c += in_sizes[fidx[k]];
        }
        ca.cum[14] = c;
        k_conv_all<<<(c + 255) / 256, 256, 0, stream>>>(ca, flag);
    }

    // merged weight swizzles
    {
        SwzArgs sa;
        const float* srcs[9] = {We0C, We1C, Wv0C, WlwC, WlwC + 256 * 16,
                                Wly1C, Wly1C + 272 * 256, Wly2C, Wly2C + 256 * 256};
        __hip_bfloat16* dsts[9] = {We0s, We1s, Wv0s, Wlws0, Wlws1, W1s0, W1s1, W2s0, W2s1};
        int Ks[9]    = {40, 256, 256, 256, 256, 272, 272, 256, 256};
        int Ncs[9]   = {256, 256, 16, 16, 16, 256, 256, 256, 256};
        int Kpads[9] = {64, 256, 256, 256, 256, 288, 288, 256, 256};
        int c = 0;
        for (int j = 0; j < 9; j++) {
            sa.src[j] = srcs[j]; sa.dst[j] = dsts[j];
            sa.K[j] = Ks[j]; sa.Nc[j] = Ncs[j];
            sa.cum[j] = c;
            c += (Kpads[j] >> 5) * Ncs[j] * 32;
        }
        sa.cum[9] = c;
        k_swz_all<<<(c + 255) / 256, 256, 0, stream>>>(sa);
    }
    k_swz_wout<<<16, 256, 0, stream>>>(WoutC, Wouts);

    // sender CSR
    hipMemsetAsync(cnt, 0, (size_t)N * sizeof(int), stream);
    k_hist<<<(E + 255) / 256, 256, 0, stream>>>(snd, cnt, E);
    k_scan<<<1, 256, 0, stream>>>(cnt, offb, cur, N);
    k_cscatter<<<(E + 255) / 256, 256, 0, stream>>>(snd, cur, eidx, E);

    // embed (fused geometry)
    k_embed_mfma<<<nb64, 512, 0, stream>>>(vecC, naC, snd, rcv,
                                           We0s, be0C, We1s, be1C, Wv0s, Wlws0,
                                           ubuf, Ybuf, xbuf, abuf, wbuf);

    // layer 0: gather0 emits wYn0 + vv0; layer kernel emits w for layer 1
    k_gather0<<<N / 4, 256, 0, stream>>>(offb, eidx, wbuf, Ybuf, abuf, wYn0, vvbuf);
    k_layer_mfma<<<nb64, 512, 0, stream>>>(xbuf, ubuf, vvbuf, rcv,
                                           W1s0, bly1C, W2s0, bly2C,
                                           Wlws1, wbuf,
                                           (const __hip_bfloat16*)nullptr, (float*)nullptr, 0);
    // layer 1: gather1 emits vv1 (wYn1 kept local); fused out-proj -> nacc
    hipMemsetAsync(nacc, 0, (size_t)N * sizeof(float), stream);
    k_gather1<<<N / 4, 256, 0, stream>>>(offb, eidx, wbuf, Ybuf, abuf, wYn0, WlshC, vvbuf);
    k_layer_mfma<<<nb64, 512, 0, stream>>>(xbuf, ubuf, vvbuf, rcv,
                                           W1s1, bly1C + H, W2s1, bly2C + H,
                                           (const __hip_bfloat16*)nullptr, (float*)nullptr,
                                           Wouts, nacc, 1);

    k_final<<<(N + 255) / 256, 256, 0, stream>>>(nacc, d_out, flag, inv, N);
}